// Round 12
// baseline (294.263 us; speedup 1.0000x reference)
//
#include <hip/hip_runtime.h>
#include <hip/hip_bf16.h>
#include <cstdint>
#include <cstddef>

#define DIMM 2048
#define NHEADS 32
#define HDIM 64
#define SEQ 2048
#define NBATCH 2
#define ROWS 4096
#define NFREQ 16
#define NKT3 32  // K=2048 / BK=64
#define QSCALE 0.1803368802f  // 0.125 * log2(e): folded into q -> softmax in exp2 domain

// prep_kernel block ranges
#define PB_LN ROWS                           // 4096
#define PB_TQKV (192 * 64)                   // 12288
#define PB_TOUT (64 * 64)                    // 4096
#define PB_ROPE ((SEQ * NFREQ + 255) / 256)  // 128
#define PB_TOTAL (PB_LN + PB_TQKV + PB_TOUT + PB_ROPE)

typedef __bf16 bfv8 __attribute__((ext_vector_type(8)));
typedef float f32x4v __attribute__((ext_vector_type(4)));
typedef float f32x16 __attribute__((ext_vector_type(16)));

__device__ __forceinline__ void gload16(const void* g, void* l) {
  __builtin_amdgcn_global_load_lds((const __attribute__((address_space(1))) void*)g,
                                   (__attribute__((address_space(3))) void*)l, 16, 0, 0);
}

__device__ __forceinline__ f32x4v mfma16(bfv8 a, bfv8 b, f32x4v c) {
  return __builtin_amdgcn_mfma_f32_16x16x32_bf16(a, b, c, 0, 0, 0);
}

__device__ __forceinline__ f32x16 mfma32(bfv8 a, bfv8 b, f32x16 c) {
  return __builtin_amdgcn_mfma_f32_32x32x16_bf16(a, b, c, 0, 0, 0);
}

__device__ __forceinline__ unsigned short f2bfu(float f) {
  __hip_bfloat16 h = __float2bfloat16(f);
  return __builtin_bit_cast(unsigned short, h);
}

__device__ __forceinline__ void swap32(unsigned& a, unsigned& b, const int hi) {
  const unsigned ta = (unsigned)__shfl_xor((int)a, 32);
  const unsigned tb = (unsigned)__shfl_xor((int)b, 32);
  const unsigned na = hi ? tb : a;
  const unsigned nb = hi ? b : ta;
  a = na;
  b = nb;
}

__device__ __forceinline__ void xcd_swizzle(int& bx, int& by) {
  const int gx = gridDim.x, nwg = gx * gridDim.y;
  const int orig = blockIdx.y * gx + blockIdx.x;
  const int q = nwg >> 3, r = nwg & 7;
  const int xcd = orig & 7, loc = orig >> 3;
  const int wg = (xcd < r ? xcd * (q + 1) : r * (q + 1) + (xcd - r) * q) + loc;
  bx = wg % gx;
  by = wg / gx;
}

// ---------------- fused prep: LN | transpose(w_qkv) | transpose(w_out) | rope ----------
__device__ __forceinline__ void transpose32_body(const float* __restrict__ W,
                                                 __hip_bfloat16* __restrict__ WT,
                                                 int K, int N, int n0, int k0,
                                                 float* tile /*[32][33]*/) {
  const int tid = threadIdx.x;
  const int tx = tid & 31, ty = tid >> 5;
#pragma unroll
  for (int j = 0; j < 4; ++j)
    tile[(ty + j * 8) * 33 + tx] = W[(size_t)(k0 + ty + j * 8) * N + n0 + tx];
  __syncthreads();
#pragma unroll
  for (int j = 0; j < 4; ++j)
    WT[(size_t)(n0 + ty + j * 8) * K + k0 + tx] = __float2bfloat16(tile[tx * 33 + ty + j * 8]);
}

__global__ __launch_bounds__(256) void prep_kernel(
    const float* __restrict__ x, const float* __restrict__ lw, const float* __restrict__ lb,
    __hip_bfloat16* __restrict__ h, const float* __restrict__ w_qkv,
    __hip_bfloat16* __restrict__ wqkvT, const float* __restrict__ w_out,
    __hip_bfloat16* __restrict__ woutT, float* __restrict__ ct, float* __restrict__ st) {
  __shared__ float pls[32 * 33];
  const int b = blockIdx.x;
  const int t = threadIdx.x;
  if (b < PB_LN) {
    const int row = b;
    const float4* xr = (const float4*)(x + (size_t)row * DIMM);
    float4 a = xr[t * 2], bb4 = xr[t * 2 + 1];
    float e[8];
    *(float4*)e = a; *(float4*)(e + 4) = bb4;
    float s = 0.f, ss = 0.f;
#pragma unroll
    for (int j = 0; j < 8; ++j) { s += e[j]; ss += e[j] * e[j]; }
#pragma unroll
    for (int o = 1; o < 64; o <<= 1) { s += __shfl_xor(s, o); ss += __shfl_xor(ss, o); }
    float* red = pls;
    const int wid = t >> 6;
    if ((t & 63) == 0) { red[wid * 2] = s; red[wid * 2 + 1] = ss; }
    __syncthreads();
    s = red[0] + red[2] + red[4] + red[6];
    ss = red[1] + red[3] + red[5] + red[7];
    const float mu = s * (1.f / DIMM);
    const float var = ss * (1.f / DIMM) - mu * mu;
    const float rs = rsqrtf(var + 1e-5f);
    const float4* w4 = (const float4*)lw;
    const float4* b4 = (const float4*)lb;
    float4 wa = w4[t * 2], wb = w4[t * 2 + 1], ba = b4[t * 2], bb = b4[t * 2 + 1];
    float wv[8], bv[8];
    *(float4*)wv = wa; *(float4*)(wv + 4) = wb;
    *(float4*)bv = ba; *(float4*)(bv + 4) = bb;
    unsigned short hv[8];
#pragma unroll
    for (int j = 0; j < 8; ++j)
      hv[j] = f2bfu((e[j] - mu) * rs * wv[j] + bv[j]);
    *(uint4*)((char*)h + (size_t)row * (DIMM * 2) + t * 16) = *(uint4*)hv;
  } else if (b < PB_LN + PB_TQKV) {
    const int i = b - PB_LN;
    const int n0 = (i % 192) * 32, k0 = (i / 192) * 32;
    transpose32_body(w_qkv, wqkvT, DIMM, 3 * DIMM, n0, k0, pls);
  } else if (b < PB_LN + PB_TQKV + PB_TOUT) {
    const int i = b - PB_LN - PB_TQKV;
    const int n0 = (i % 64) * 32, k0 = (i / 64) * 32;
    transpose32_body(w_out, woutT, DIMM, DIMM, n0, k0, pls);
  } else {
    const int i = (b - PB_LN - PB_TQKV - PB_TOUT) * 256 + t;
    if (i < SEQ * NFREQ) {
      const int pos = i >> 4, f = i & 15;
      const float freq = powf(10000.0f, -(float)f / 16.0f);
      const float ang = (float)pos * freq;
      ct[i] = cosf(ang);
      st[i] = sinf(ang);
    }
  }
}

// ======== 256x128xK GEMM, BK=64, 8 waves = 2M x 2N x 2K, ring-3 LDS (R7, proven) ========
__device__ __forceinline__ void stageA64(const char* Ab, int brow, int kt,
                                         char* bufA, int c, int lane) {
  const int row = c * 8 + (lane >> 3);
  const int src = ((lane & 7) * 16) ^ ((row & 7) << 4);
  gload16(Ab + (size_t)(brow + row) * 4096 + kt * 128 + src, bufA + c * 1024);
}
__device__ __forceinline__ void stageB64(const char* Bb, int bcol, int kt,
                                         char* bufB, int c, int lane) {
  const int row = c * 8 + (lane >> 3);
  const int src = ((lane & 7) * 16) ^ ((row & 7) << 4);
  gload16(Bb + (size_t)(bcol + row) * 4096 + kt * 128 + src, bufB + c * 1024);
}

__device__ __forceinline__ void gemm_core3(const char* Ab, const char* Bb,
                                           int brow, int bcol, char* lds,
                                           f32x4v acc[8][4]) {
  const int tid = threadIdx.x, lane = tid & 63, wid = tid >> 6;
  const int g = lane >> 4, ln15 = lane & 15;
  const int wr = wid >> 2, wc = (wid >> 1) & 1, wk = wid & 1;
  const int kb = wk * 64;
#pragma unroll
  for (int t = 0; t < 2; ++t) {
    char* bufA = lds + t * 49152;
    char* bufB = bufA + 32768;
    stageA64(Ab, brow, t, bufA, wid, lane);
    stageA64(Ab, brow, t, bufA, wid + 8, lane);
    stageA64(Ab, brow, t, bufA, wid + 16, lane);
    stageA64(Ab, brow, t, bufA, wid + 24, lane);
    stageB64(Bb, bcol, t, bufB, wid, lane);
    stageB64(Bb, bcol, t, bufB, wid + 8, lane);
  }
  asm volatile("s_waitcnt vmcnt(6)" ::: "memory");
  __builtin_amdgcn_s_barrier();

  for (int t = 0; t < NKT3; ++t) {
    char* bufA = lds + (t % 3) * 49152;
    char* bufB = bufA + 32768;
    char* nbufA = lds + ((t + 2) % 3) * 49152;
    char* nbufB = nbufA + 32768;
    const bool st = (t + 2 < NKT3);
    bfv8 af[4], bfr[4];
#pragma unroll
    for (int mi = 0; mi < 4; ++mi) {
      const int ra = wr * 128 + mi * 16 + ln15;
      af[mi] = *(const bfv8*)(bufA + (size_t)ra * 128 + ((kb + g * 16) ^ ((ra & 7) << 4)));
    }
#pragma unroll
    for (int nf = 0; nf < 4; ++nf) {
      const int rb = wc * 64 + nf * 16 + ln15;
      bfr[nf] = *(const bfv8*)(bufB + (size_t)rb * 128 + ((kb + g * 16) ^ ((rb & 7) << 4)));
    }
    if (st) {
      stageA64(Ab, brow, t + 2, nbufA, wid, lane);
      stageA64(Ab, brow, t + 2, nbufA, wid + 8, lane);
      stageB64(Bb, bcol, t + 2, nbufB, wid, lane);
    }
    __builtin_amdgcn_s_setprio(1);
#pragma unroll
    for (int mi = 0; mi < 4; ++mi)
#pragma unroll
      for (int nf = 0; nf < 4; ++nf)
        acc[mi][nf] = mfma16(af[mi], bfr[nf], acc[mi][nf]);
    __builtin_amdgcn_s_setprio(0);
    bfv8 ao[4];
#pragma unroll
    for (int mi = 0; mi < 4; ++mi) {
      const int ra = wr * 128 + (4 + mi) * 16 + ln15;
      ao[mi] = *(const bfv8*)(bufA + (size_t)ra * 128 + ((kb + g * 16) ^ ((ra & 7) << 4)));
    }
    if (st) {
      stageA64(Ab, brow, t + 2, nbufA, wid + 16, lane);
      stageA64(Ab, brow, t + 2, nbufA, wid + 24, lane);
      stageB64(Bb, bcol, t + 2, nbufB, wid + 8, lane);
    }
    __builtin_amdgcn_s_setprio(1);
#pragma unroll
    for (int mi = 0; mi < 4; ++mi)
#pragma unroll
      for (int nf = 0; nf < 4; ++nf)
        acc[4 + mi][nf] = mfma16(ao[mi], bfr[nf], acc[4 + mi][nf]);
    __builtin_amdgcn_s_setprio(0);
    if (st) {
      asm volatile("s_waitcnt vmcnt(6)" ::: "memory");
    } else if (t == NKT3 - 2) {
      asm volatile("s_waitcnt vmcnt(0)" ::: "memory");
    }
    asm volatile("" ::: "memory");
    __builtin_amdgcn_s_barrier();
  }
}

__device__ __forceinline__ void kreduce(char* lds, f32x4v acc[8][4], f32x4v ak[4][4],
                                        int wid, int lane, int wk) {
  char* reg = lds + (size_t)wid * 16384;
#pragma unroll
  for (int q = 0; q < 4; ++q)
#pragma unroll
    for (int nf = 0; nf < 4; ++nf)
      *(f32x4v*)(reg + (q * 4 + nf) * 1024 + lane * 16) = acc[wk ? q : 4 + q][nf];
  __syncthreads();
  const char* preg = lds + (size_t)(wid ^ 1) * 16384;
#pragma unroll
  for (int q = 0; q < 4; ++q)
#pragma unroll
    for (int nf = 0; nf < 4; ++nf)
      ak[q][nf] = acc[wk ? 4 + q : q][nf] +
                  *(const f32x4v*)(preg + (q * 4 + nf) * 1024 + lane * 16);
  __syncthreads();
}

// ---------------- QKV GEMM + bias + RoPE (q pre-scaled by QSCALE); v -> VT ----------------
__global__ __launch_bounds__(512, 2) void gemm_qkv_kernel(
    const __hip_bfloat16* __restrict__ A, const __hip_bfloat16* __restrict__ BT,
    const float* __restrict__ bqkv, const float* __restrict__ ct, const float* __restrict__ st,
    __hip_bfloat16* __restrict__ qb, __hip_bfloat16* __restrict__ kb,
    __hip_bfloat16* __restrict__ vb) {
  __shared__ char lds[147456];
  const f32x4v fz = {0.f, 0.f, 0.f, 0.f};
  f32x4v acc[8][4];
#pragma unroll
  for (int mf = 0; mf < 8; ++mf)
#pragma unroll
    for (int nf = 0; nf < 4; ++nf) acc[mf][nf] = fz;
  int bx, by;
  xcd_swizzle(bx, by);
  const int brow = by * 256, bcol = bx * 128;
  gemm_core3((const char*)A, (const char*)BT, brow, bcol, lds, acc);

  const int tid = threadIdx.x, lane = tid & 63, wid = tid >> 6;
  const int g = lane >> 4, ln15 = lane & 15;
  const int wr = wid >> 2, wc = (wid >> 1) & 1, wk = wid & 1;
  f32x4v ak[4][4];
  kreduce(lds, acc, ak, wid, lane, wk);

  const int cb = bcol + wc * 64;
  const int which = cb >> 11;
  const int head = (cb & 2047) >> 6;
  const int rowbase = brow + wr * 128 + wk * 64;
  const int nidx = rowbase >> 11;
  const int posb = rowbase & 2047;
  float bias[4];
#pragma unroll
  for (int nf = 0; nf < 4; ++nf) bias[nf] = bqkv[cb + nf * 16 + ln15];

  if (which == 2) {
    char* tp = lds + wid * 8192;
    const size_t vhead = ((size_t)nidx * NHEADS + head) * (HDIM * SEQ);
#pragma unroll
    for (int q = 0; q < 4; ++q)
#pragma unroll
      for (int r = 0; r < 4; ++r) {
        const int posl = q * 16 + g * 4 + r;
#pragma unroll
        for (int nf = 0; nf < 4; ++nf) {
          const int d = nf * 16 + ln15;
          *(unsigned short*)(tp + d * 128 + ((posl * 2) ^ ((d & 7) << 4))) =
              f2bfu(ak[q][nf][r] + bias[nf]);
        }
      }
    asm volatile("s_waitcnt lgkmcnt(0)" ::: "memory");
    __builtin_amdgcn_sched_barrier(0);
#pragma unroll
    for (int i = 0; i < 8; ++i) {
      const int dl = i * 8 + (lane >> 3);
      const int cs = (lane & 7) ^ (dl & 7);
      const uint4 val = *(const uint4*)(tp + dl * 128 + cs * 16);
      *(uint4*)((char*)vb + (vhead + (size_t)dl * SEQ + posb + (lane & 7) * 8) * 2) = val;
    }
  } else {
    __hip_bfloat16* dst = (which == 0) ? qb : kb;
    const float qs = (which == 0) ? QSCALE : 1.0f;
    char* tp = lds + wid * 8192;
#pragma unroll
    for (int q = 0; q < 4; ++q)
#pragma unroll
      for (int r = 0; r < 4; ++r) {
        const int posl = q * 16 + g * 4 + r;
        const int pos = posb + posl;
        float v0 = ak[q][0][r] + bias[0];
        float v1 = ak[q][1][r] + bias[1];
        float v2 = ak[q][2][r] + bias[2];
        float v3 = ak[q][3][r] + bias[3];
        const float c0 = ct[pos * 16 + ln15], s0 = st[pos * 16 + ln15];
        const float x1 = v0, x2 = v1;
        v0 = (x1 * c0 - x2 * s0) * qs;
        v1 = (x2 * c0 + x1 * s0) * qs;
        v2 *= qs;
        v3 *= qs;
        const int sw2 = (posl & 7) << 4;
        char* rowp = tp + posl * 128;
        *(unsigned short*)(rowp + ((ln15 * 2) ^ sw2)) = f2bfu(v0);
        *(unsigned short*)(rowp + ((32 + ln15 * 2) ^ sw2)) = f2bfu(v1);
        *(unsigned short*)(rowp + ((64 + ln15 * 2) ^ sw2)) = f2bfu(v2);
        *(unsigned short*)(rowp + ((96 + ln15 * 2) ^ sw2)) = f2bfu(v3);
      }
    asm volatile("s_waitcnt lgkmcnt(0)" ::: "memory");
    __builtin_amdgcn_sched_barrier(0);
    const size_t qkbase = (((size_t)(nidx * NHEADS + head)) * SEQ + posb) * HDIM;
#pragma unroll
    for (int i = 0; i < 8; ++i) {
      const int rr = i * 8 + (lane >> 3);
      const int cs = (lane & 7) ^ (rr & 7);
      const uint4 val = *(const uint4*)(tp + rr * 128 + cs * 16);
      *(uint4*)((char*)dst + (qkbase + (size_t)rr * HDIM) * 2 + (lane & 7) * 16) = val;
    }
  }
}

// ---------------- out-proj GEMM + bias + residual -> f32 out (LDS-repacked) ----------
__global__ __launch_bounds__(512, 2) void gemm_out_kernel(
    const __hip_bfloat16* __restrict__ A, const __hip_bfloat16* __restrict__ BT,
    const float* __restrict__ bout, const float* __restrict__ skip,
    float* __restrict__ out) {
  __shared__ char lds[147456];
  const f32x4v fz = {0.f, 0.f, 0.f, 0.f};
  f32x4v acc[8][4];
#pragma unroll
  for (int mf = 0; mf < 8; ++mf)
#pragma unroll
    for (int nf = 0; nf < 4; ++nf) acc[mf][nf] = fz;
  int bx, by;
  xcd_swizzle(bx, by);
  const int brow = by * 256, bcol = bx * 128;
  gemm_core3((const char*)A, (const char*)BT, brow, bcol, lds, acc);

  const int tid = threadIdx.x, lane = tid & 63, wid = tid >> 6;
  const int g = lane >> 4, ln15 = lane & 15;
  const int wr = wid >> 2, wc = (wid >> 1) & 1, wk = wid & 1;
  f32x4v ak[4][4];
  kreduce(lds, acc, ak, wid, lane, wk);

  const int rowbase = brow + wr * 128 + wk * 64;
  char* tp = lds + wid * 16384;
#pragma unroll
  for (int q = 0; q < 4; ++q)
#pragma unroll
    for (int r = 0; r < 4; ++r) {
      const int posl = q * 16 + g * 4 + r;
      const int sw2 = ((posl >> 2) & 3) << 6;
      char* rowp = tp + posl * 256;
#pragma unroll
      for (int nf = 0; nf < 4; ++nf)
        *(float*)(rowp + ((nf * 64 + ln15 * 4) ^ sw2)) = ak[q][nf][r];
    }
  asm volatile("s_waitcnt lgkmcnt(0)" ::: "memory");
  __builtin_amdgcn_sched_barrier(0);
  const int colb = bcol + wc * 64;
#pragma unroll
  for (int i = 0; i < 16; ++i) {
    const int rr = i * 4 + (lane >> 4);
    const int cp = lane & 15;
    const float4 a4 = *(const float4*)(tp + rr * 256 + cp * 16);
    const int lc = (cp * 16) ^ (((rr >> 2) & 3) << 6);
    const int col = colb + (lc >> 2);
    const int row = rowbase + rr;
    const float4 sk = *(const float4*)(skip + (size_t)row * DIMM + col);
    const float4 bo = *(const float4*)(bout + col);
    float4 o4;
    o4.x = a4.x + sk.x + bo.x;
    o4.y = a4.y + sk.y + bo.y;
    o4.z = a4.z + sk.z + bo.z;
    o4.w = a4.w + sk.w + bo.w;
    *(float4*)(out + (size_t)row * DIMM + col) = o4;
  }
}

// ------- causal flash attention: 2-deep score pipeline (QK(t+1) || softmax(t)) -------
// Ring-3 KV bufs; exp2-domain softmax in-place on score registers; nt always even.
__global__ __launch_bounds__(256) void attn_kernel(
    const __hip_bfloat16* __restrict__ qb, const __hip_bfloat16* __restrict__ kb,
    const __hip_bfloat16* __restrict__ vtb, __hip_bfloat16* __restrict__ ob) {
  __shared__ char sm[49664];
  float* lred = (float*)(sm + 49152);
  const int tid = threadIdx.x, lane = tid & 63, wid = tid >> 6;
  const int ln31 = lane & 31, hi = lane >> 5;
  const int head = blockIdx.x;
  const int qbi = (int)gridDim.y - 1 - (int)blockIdx.y;  // heavy blocks dispatch first
  const size_t hb = (size_t)head * (SEQ * HDIM);
  const int q0 = qbi * 128;
  const int qw = q0 + wid * 32;
  const int qg = qw + ln31;
  const int nt = qbi * 2 + 2;  // always even
  const char* Kg = (const char*)(kb + hb);
  const char* Vg = (const char*)(vtb + hb);

  bfv8 qf[4];
  {
    const char* Qp = (const char*)(qb + hb) + (size_t)(qw + ln31) * 128 + hi * 16;
#pragma unroll
    for (int j = 0; j < 4; ++j) qf[j] = *(const bfv8*)(Qp + j * 32);
  }

  f32x16 o0, o1;
#pragma unroll
  for (int i = 0; i < 16; ++i) { o0[i] = 0.f; o1[i] = 0.f; }
  float m_run = -1e30f, l_run = 0.f;
  const int swz = (ln31 & 7) << 4;

#define ATTN_STAGE(T, B)                                                            \
  {                                                                                 \
    const int kvs = (T)*64;                                                         \
    _Pragma("unroll") for (int i = 0; i < 2; ++i) {                                 \
      const int f = (tid + i * 256) * 16;                                           \
      const int row = f >> 7;                                                       \
      const int src = (f & 127) ^ ((row & 7) << 4);                                 \
      gload16(Kg + (size_t)(kvs + row) * 128 + src, sm + (B)*8192 + f);             \
      gload16(Vg + (size_t)row * 4096 + (size_t)kvs * 2 + src,                      \
              sm + 24576 + (B)*8192 + f);                                           \
    }                                                                               \
  }

  // QK^T of tile (kv base in exp2 units) from K-ring buffer b into d0/d1
  auto qk_tile = [&](int b, f32x16& d0, f32x16& d1) {
    const char* ldsK = sm + b * 8192;
    f32x16 a0, a1;
#pragma unroll
    for (int i = 0; i < 16; ++i) { a0[i] = 0.f; a1[i] = 0.f; }
    __builtin_amdgcn_s_setprio(1);
#pragma unroll
    for (int j = 0; j < 4; ++j) {
      const int byt = j * 32 + hi * 16;
      const bfv8 k0 = *(const bfv8*)(ldsK + ln31 * 128 + (byt ^ swz));
      const bfv8 k1 = *(const bfv8*)(ldsK + (32 + ln31) * 128 + (byt ^ swz));
      a0 = mfma32(k0, qf[j], a0);
      a1 = mfma32(k1, qf[j], a1);
    }
    __builtin_amdgcn_s_setprio(0);
    d0 = a0;
    d1 = a1;
  };

  // softmax (in place on s0/s1) + PV accumulate, for tile at kvb with V in ring buf b
  auto sm_pv = [&](f32x16& s0, f32x16& s1, int kvb, int b) {
    const char* ldsV = sm + 24576 + b * 8192;
    if (kvb + 63 > qw) {  // diagonal tile for this wave (compare vs MIN q-row)
#pragma unroll
      for (int r = 0; r < 16; ++r) {
        const int kvo = (r & 3) + 8 * (r >> 2) + 4 * hi;
        if (kvb + kvo > qg) s0[r] = -1e30f;
        if (kvb + 32 + kvo > qg) s1[r] = -1e30f;
      }
    }
    float m8[8];
#pragma unroll
    for (int r = 0; r < 8; ++r)
      m8[r] = fmaxf(fmaxf(s0[r], s0[8 + r]), fmaxf(s1[r], s1[8 + r]));
    float m4a = fmaxf(m8[0], m8[4]), m4b = fmaxf(m8[1], m8[5]);
    float m4c = fmaxf(m8[2], m8[6]), m4d = fmaxf(m8[3], m8[7]);
    float mx = fmaxf(fmaxf(m4a, m4b), fmaxf(m4c, m4d));
    mx = fmaxf(mx, __shfl_xor(mx, 32));
    if (!__all(mx <= m_run + 8.0f)) {  // defer-max: P bounded by 2^8
      const float mn = fmaxf(m_run, mx);
      const float al = __builtin_amdgcn_exp2f(m_run - mn);
      m_run = mn;
      l_run *= al;
      lred[wid * 32 + ln31] = al;
      asm volatile("s_waitcnt lgkmcnt(0)" ::: "memory");
      __builtin_amdgcn_sched_barrier(0);
#pragma unroll
      for (int r = 0; r < 16; ++r) {
        const float a = lred[wid * 32 + (r & 3) + 8 * (r >> 2) + 4 * hi];
        o0[r] *= a;
        o1[r] *= a;
      }
    }
    float ps = 0.f;
#pragma unroll
    for (int r = 0; r < 16; ++r) {
      s0[r] = __builtin_amdgcn_exp2f(s0[r] - m_run);
      s1[r] = __builtin_amdgcn_exp2f(s1[r] - m_run);
      ps += s0[r] + s1[r];
    }
    ps += __shfl_xor(ps, 32);
    l_run += ps;
    unsigned c[16];
#pragma unroll
    for (int i = 0; i < 8; ++i) {
      unsigned r0, r1;
      asm("v_cvt_pk_bf16_f32 %0, %1, %2" : "=v"(r0) : "v"(s0[2 * i]), "v"(s0[2 * i + 1]));
      asm("v_cvt_pk_bf16_f32 %0, %1, %2" : "=v"(r1) : "v"(s1[2 * i]), "v"(s1[2 * i + 1]));
      c[i] = r0;
      c[8 + i] = r1;
    }
    bfv8 paf[4];
#pragma unroll
    for (int fI = 0; fI < 4; ++fI) {
      unsigned a0 = c[fI * 4 + 0], b0 = c[fI * 4 + 2];
      unsigned a1 = c[fI * 4 + 1], b1 = c[fI * 4 + 3];
      swap32(a0, b0, hi);
      swap32(a1, b1, hi);
      union { unsigned u[4]; bfv8 v; } w;
      w.u[0] = a0; w.u[1] = a1; w.u[2] = b0; w.u[3] = b1;
      paf[fI] = w.v;
    }
    __builtin_amdgcn_s_setprio(1);
#pragma unroll
    for (int ss = 0; ss < 4; ++ss) {
      const int byt = ss * 32 + hi * 16;
      const bfv8 v0 = *(const bfv8*)(ldsV + ln31 * 128 + (byt ^ swz));
      const bfv8 v1 = *(const bfv8*)(ldsV + (32 + ln31) * 128 + (byt ^ swz));
      o0 = mfma32(paf[ss], v0, o0);
      o1 = mfma32(paf[ss], v1, o1);
    }
    __builtin_amdgcn_s_setprio(0);
  };

  // prologue: stage tiles 0,1; drain; QK of tile 0 into sA
  ATTN_STAGE(0, 0);
  if (nt > 1) ATTN_STAGE(1, 1);
  asm volatile("s_waitcnt vmcnt(0)" ::: "memory");
  __builtin_amdgcn_s_barrier();
  f32x16 sA0, sA1, sB0, sB1;
  qk_tile(0, sA0, sA1);

  for (int t = 0; t < nt; t += 2) {
    // ---- body A: tile t (sA); lookahead QK(t+1) -> sB; stage t+2 ----
    if (t + 2 < nt) ATTN_STAGE(t + 2, (t + 2) % 3);
    if ((t + 1) * 64 <= qw + 31) qk_tile((t + 1) % 3, sB0, sB1);
    if (t * 64 <= qw + 31) sm_pv(sA0, sA1, t * 64, t % 3);
    asm volatile("s_waitcnt vmcnt(0)" ::: "memory");
    __builtin_amdgcn_s_barrier();
    // ---- body B: tile t+1 (sB); lookahead QK(t+2) -> sA; stage t+3 ----
    if (t + 3 < nt) ATTN_STAGE(t + 3, (t + 3) % 3);
    if (t + 2 < nt && (t + 2) * 64 <= qw + 31) qk_tile((t + 2) % 3, sA0, sA1);
    if ((t + 1) * 64 <= qw + 31) sm_pv(sB0, sB1, (t + 1) * 64, (t + 1) % 3);
    asm volatile("s_waitcnt vmcnt(0)" ::: "memory");
    __builtin_amdgcn_s_barrier();
  }
#undef ATTN_STAGE

  lred[wid * 32 + ln31] = l_run;
  asm volatile("s_waitcnt lgkmcnt(0)" ::: "memory");
  __builtin_amdgcn_sched_barrier(0);
  const int nidx = head >> 5, hh = head & 31;
#pragma unroll
  for (int r = 0; r < 16; ++r) {
    const int qrow = qw + (r & 3) + 8 * (r >> 2) + 4 * hi;
    const float inv = 1.0f / lred[wid * 32 + (r & 3) + 8 * (r >> 2) + 4 * hi];
    __hip_bfloat16* dst = ob + ((size_t)nidx * SEQ + qrow) * DIMM + hh * 64;
    dst[ln31] = __float2bfloat16(o0[r] * inv);
    dst[32 + ln31] = __float2bfloat16(o1[r] * inv);
  }
}

extern "C" void kernel_launch(void* const* d_in, const int* in_sizes, int n_in,
                              void* d_out, int out_size, void* d_ws, size_t ws_size,
                              hipStream_t stream) {
  const float* x = (const float*)d_in[0];
  const float* ln_w = (const float*)d_in[1];
  const float* ln_b = (const float*)d_in[2];
  const float* w_qkv = (const float*)d_in[3];
  const float* b_qkv = (const float*)d_in[4];
  const float* w_out = (const float*)d_in[5];
  const float* b_out = (const float*)d_in[6];
  float* out = (float*)d_out;

  char* ws = (char*)d_ws;
  size_t off = 0;
  auto alloc = [&](size_t bytes) -> char* {
    char* p = ws + off;
    off += (bytes + 255) & ~(size_t)255;
    return p;
  };
  __hip_bfloat16* h = (__hip_bfloat16*)alloc((size_t)ROWS * DIMM * 2);
  __hip_bfloat16* wqkvT = (__hip_bfloat16*)alloc((size_t)3 * DIMM * DIMM * 2);
  __hip_bfloat16* woutT = (__hip_bfloat16*)alloc((size_t)DIMM * DIMM * 2);
  __hip_bfloat16* qbuf = (__hip_bfloat16*)alloc((size_t)ROWS * DIMM * 2);
  __hip_bfloat16* kbuf = (__hip_bfloat16*)alloc((size_t)ROWS * DIMM * 2);
  __hip_bfloat16* vtbuf = (__hip_bfloat16*)alloc((size_t)ROWS * DIMM * 2);
  __hip_bfloat16* obuf = (__hip_bfloat16*)alloc((size_t)ROWS * DIMM * 2);
  float* ct = (float*)alloc((size_t)SEQ * NFREQ * 4);
  float* st = (float*)alloc((size_t)SEQ * NFREQ * 4);

  prep_kernel<<<dim3(PB_TOTAL), dim3(256), 0, stream>>>(
      x, ln_w, ln_b, h, w_qkv, wqkvT, w_out, woutT, ct, st);
  gemm_qkv_kernel<<<dim3(3 * DIMM / 128, ROWS / 256), dim3(512), 0, stream>>>(
      h, wqkvT, b_qkv, ct, st, qbuf, kbuf, vtbuf);
  attn_kernel<<<dim3(NBATCH * NHEADS, SEQ / 128), dim3(256), 0, stream>>>(
      qbuf, kbuf, vtbuf, obuf);
  gemm_out_kernel<<<dim3(DIMM / 128, ROWS / 256), dim3(512), 0, stream>>>(
      obuf, woutT, b_out, x, out);
}

// Round 13
// 263.112 us; speedup vs baseline: 1.1184x; 1.1184x over previous
//
#include <hip/hip_runtime.h>
#include <hip/hip_bf16.h>
#include <cstdint>
#include <cstddef>

#define DIMM 2048
#define NHEADS 32
#define HDIM 64
#define SEQ 2048
#define NBATCH 2
#define ROWS 4096
#define NFREQ 16
#define NKT3 32  // K=2048 / BK=64
#define QSCALE 0.1803368802f  // 0.125 * log2(e): folded into q -> softmax in exp2 domain

// prep_kernel block ranges
#define PB_LN ROWS                           // 4096
#define PB_TQKV (192 * 64)                   // 12288
#define PB_TOUT (64 * 64)                    // 4096
#define PB_ROPE ((SEQ * NFREQ + 255) / 256)  // 128
#define PB_TOTAL (PB_LN + PB_TQKV + PB_TOUT + PB_ROPE)

typedef __bf16 bfv8 __attribute__((ext_vector_type(8)));
typedef float f32x4v __attribute__((ext_vector_type(4)));
typedef float f32x16 __attribute__((ext_vector_type(16)));

__device__ __forceinline__ void gload16(const void* g, void* l) {
  __builtin_amdgcn_global_load_lds((const __attribute__((address_space(1))) void*)g,
                                   (__attribute__((address_space(3))) void*)l, 16, 0, 0);
}

__device__ __forceinline__ f32x4v mfma16(bfv8 a, bfv8 b, f32x4v c) {
  return __builtin_amdgcn_mfma_f32_16x16x32_bf16(a, b, c, 0, 0, 0);
}

__device__ __forceinline__ f32x16 mfma32(bfv8 a, bfv8 b, f32x16 c) {
  return __builtin_amdgcn_mfma_f32_32x32x16_bf16(a, b, c, 0, 0, 0);
}

__device__ __forceinline__ unsigned short f2bfu(float f) {
  __hip_bfloat16 h = __float2bfloat16(f);
  return __builtin_bit_cast(unsigned short, h);
}

__device__ __forceinline__ unsigned pack2bf(float a, float b) {
  return (unsigned)f2bfu(a) | ((unsigned)f2bfu(b) << 16);
}

__device__ __forceinline__ void swap32(unsigned& a, unsigned& b, const int hi) {
  const unsigned ta = (unsigned)__shfl_xor((int)a, 32);
  const unsigned tb = (unsigned)__shfl_xor((int)b, 32);
  const unsigned na = hi ? tb : a;
  const unsigned nb = hi ? b : ta;
  a = na;
  b = nb;
}

__device__ __forceinline__ void xcd_swizzle(int& bx, int& by) {
  const int gx = gridDim.x, nwg = gx * gridDim.y;
  const int orig = blockIdx.y * gx + blockIdx.x;
  const int q = nwg >> 3, r = nwg & 7;
  const int xcd = orig & 7, loc = orig >> 3;
  const int wg = (xcd < r ? xcd * (q + 1) : r * (q + 1) + (xcd - r) * q) + loc;
  bx = wg % gx;
  by = wg / gx;
}

// ---------------- fused prep: LN | transpose(w_qkv) | transpose(w_out) | rope ----------
__device__ __forceinline__ void transpose32_body(const float* __restrict__ W,
                                                 __hip_bfloat16* __restrict__ WT,
                                                 int K, int N, int n0, int k0,
                                                 float* tile /*[32][33]*/) {
  const int tid = threadIdx.x;
  const int tx = tid & 31, ty = tid >> 5;
#pragma unroll
  for (int j = 0; j < 4; ++j)
    tile[(ty + j * 8) * 33 + tx] = W[(size_t)(k0 + ty + j * 8) * N + n0 + tx];
  __syncthreads();
#pragma unroll
  for (int j = 0; j < 4; ++j)
    WT[(size_t)(n0 + ty + j * 8) * K + k0 + tx] = __float2bfloat16(tile[tx * 33 + ty + j * 8]);
}

__global__ __launch_bounds__(256) void prep_kernel(
    const float* __restrict__ x, const float* __restrict__ lw, const float* __restrict__ lb,
    __hip_bfloat16* __restrict__ h, const float* __restrict__ w_qkv,
    __hip_bfloat16* __restrict__ wqkvT, const float* __restrict__ w_out,
    __hip_bfloat16* __restrict__ woutT, float* __restrict__ ct, float* __restrict__ st) {
  __shared__ float pls[32 * 33];
  const int b = blockIdx.x;
  const int t = threadIdx.x;
  if (b < PB_LN) {
    const int row = b;
    const float4* xr = (const float4*)(x + (size_t)row * DIMM);
    float4 a = xr[t * 2], bb4 = xr[t * 2 + 1];
    float e[8];
    *(float4*)e = a; *(float4*)(e + 4) = bb4;
    float s = 0.f, ss = 0.f;
#pragma unroll
    for (int j = 0; j < 8; ++j) { s += e[j]; ss += e[j] * e[j]; }
#pragma unroll
    for (int o = 1; o < 64; o <<= 1) { s += __shfl_xor(s, o); ss += __shfl_xor(ss, o); }
    float* red = pls;
    const int wid = t >> 6;
    if ((t & 63) == 0) { red[wid * 2] = s; red[wid * 2 + 1] = ss; }
    __syncthreads();
    s = red[0] + red[2] + red[4] + red[6];
    ss = red[1] + red[3] + red[5] + red[7];
    const float mu = s * (1.f / DIMM);
    const float var = ss * (1.f / DIMM) - mu * mu;
    const float rs = rsqrtf(var + 1e-5f);
    const float4* w4 = (const float4*)lw;
    const float4* b4 = (const float4*)lb;
    float4 wa = w4[t * 2], wb = w4[t * 2 + 1], ba = b4[t * 2], bb = b4[t * 2 + 1];
    float wv[8], bv[8];
    *(float4*)wv = wa; *(float4*)(wv + 4) = wb;
    *(float4*)bv = ba; *(float4*)(bv + 4) = bb;
    unsigned short hv[8];
#pragma unroll
    for (int j = 0; j < 8; ++j)
      hv[j] = f2bfu((e[j] - mu) * rs * wv[j] + bv[j]);
    *(uint4*)((char*)h + (size_t)row * (DIMM * 2) + t * 16) = *(uint4*)hv;
  } else if (b < PB_LN + PB_TQKV) {
    const int i = b - PB_LN;
    const int n0 = (i % 192) * 32, k0 = (i / 192) * 32;
    transpose32_body(w_qkv, wqkvT, DIMM, 3 * DIMM, n0, k0, pls);
  } else if (b < PB_LN + PB_TQKV + PB_TOUT) {
    const int i = b - PB_LN - PB_TQKV;
    const int n0 = (i % 64) * 32, k0 = (i / 64) * 32;
    transpose32_body(w_out, woutT, DIMM, DIMM, n0, k0, pls);
  } else {
    const int i = (b - PB_LN - PB_TQKV - PB_TOUT) * 256 + t;
    if (i < SEQ * NFREQ) {
      const int pos = i >> 4, f = i & 15;
      const float freq = powf(10000.0f, -(float)f / 16.0f);
      const float ang = (float)pos * freq;
      ct[i] = cosf(ang);
      st[i] = sinf(ang);
    }
  }
}

// ======== 256x128xK GEMM, BK=64, 8 waves = 2M x 2N x 2K, ring-3 LDS (R7, proven) ========
__device__ __forceinline__ void stageA64(const char* Ab, int brow, int kt,
                                         char* bufA, int c, int lane) {
  const int row = c * 8 + (lane >> 3);
  const int src = ((lane & 7) * 16) ^ ((row & 7) << 4);
  gload16(Ab + (size_t)(brow + row) * 4096 + kt * 128 + src, bufA + c * 1024);
}
__device__ __forceinline__ void stageB64(const char* Bb, int bcol, int kt,
                                         char* bufB, int c, int lane) {
  const int row = c * 8 + (lane >> 3);
  const int src = ((lane & 7) * 16) ^ ((row & 7) << 4);
  gload16(Bb + (size_t)(bcol + row) * 4096 + kt * 128 + src, bufB + c * 1024);
}

__device__ __forceinline__ void gemm_core3(const char* Ab, const char* Bb,
                                           int brow, int bcol, char* lds,
                                           f32x4v acc[8][4]) {
  const int tid = threadIdx.x, lane = tid & 63, wid = tid >> 6;
  const int g = lane >> 4, ln15 = lane & 15;
  const int wr = wid >> 2, wc = (wid >> 1) & 1, wk = wid & 1;
  const int kb = wk * 64;
#pragma unroll
  for (int t = 0; t < 2; ++t) {
    char* bufA = lds + t * 49152;
    char* bufB = bufA + 32768;
    stageA64(Ab, brow, t, bufA, wid, lane);
    stageA64(Ab, brow, t, bufA, wid + 8, lane);
    stageA64(Ab, brow, t, bufA, wid + 16, lane);
    stageA64(Ab, brow, t, bufA, wid + 24, lane);
    stageB64(Bb, bcol, t, bufB, wid, lane);
    stageB64(Bb, bcol, t, bufB, wid + 8, lane);
  }
  asm volatile("s_waitcnt vmcnt(6)" ::: "memory");
  __builtin_amdgcn_s_barrier();

  for (int t = 0; t < NKT3; ++t) {
    char* bufA = lds + (t % 3) * 49152;
    char* bufB = bufA + 32768;
    char* nbufA = lds + ((t + 2) % 3) * 49152;
    char* nbufB = nbufA + 32768;
    const bool st = (t + 2 < NKT3);
    bfv8 af[4], bfr[4];
#pragma unroll
    for (int mi = 0; mi < 4; ++mi) {
      const int ra = wr * 128 + mi * 16 + ln15;
      af[mi] = *(const bfv8*)(bufA + (size_t)ra * 128 + ((kb + g * 16) ^ ((ra & 7) << 4)));
    }
#pragma unroll
    for (int nf = 0; nf < 4; ++nf) {
      const int rb = wc * 64 + nf * 16 + ln15;
      bfr[nf] = *(const bfv8*)(bufB + (size_t)rb * 128 + ((kb + g * 16) ^ ((rb & 7) << 4)));
    }
    if (st) {
      stageA64(Ab, brow, t + 2, nbufA, wid, lane);
      stageA64(Ab, brow, t + 2, nbufA, wid + 8, lane);
      stageB64(Bb, bcol, t + 2, nbufB, wid, lane);
    }
    __builtin_amdgcn_s_setprio(1);
#pragma unroll
    for (int mi = 0; mi < 4; ++mi)
#pragma unroll
      for (int nf = 0; nf < 4; ++nf)
        acc[mi][nf] = mfma16(af[mi], bfr[nf], acc[mi][nf]);
    __builtin_amdgcn_s_setprio(0);
    bfv8 ao[4];
#pragma unroll
    for (int mi = 0; mi < 4; ++mi) {
      const int ra = wr * 128 + (4 + mi) * 16 + ln15;
      ao[mi] = *(const bfv8*)(bufA + (size_t)ra * 128 + ((kb + g * 16) ^ ((ra & 7) << 4)));
    }
    if (st) {
      stageA64(Ab, brow, t + 2, nbufA, wid + 16, lane);
      stageA64(Ab, brow, t + 2, nbufA, wid + 24, lane);
      stageB64(Bb, bcol, t + 2, nbufB, wid + 8, lane);
    }
    __builtin_amdgcn_s_setprio(1);
#pragma unroll
    for (int mi = 0; mi < 4; ++mi)
#pragma unroll
      for (int nf = 0; nf < 4; ++nf)
        acc[4 + mi][nf] = mfma16(ao[mi], bfr[nf], acc[4 + mi][nf]);
    __builtin_amdgcn_s_setprio(0);
    if (st) {
      asm volatile("s_waitcnt vmcnt(6)" ::: "memory");
    } else if (t == NKT3 - 2) {
      asm volatile("s_waitcnt vmcnt(0)" ::: "memory");
    }
    asm volatile("" ::: "memory");
    __builtin_amdgcn_s_barrier();
  }
}

__device__ __forceinline__ void kreduce(char* lds, f32x4v acc[8][4], f32x4v ak[4][4],
                                        int wid, int lane, int wk) {
  char* reg = lds + (size_t)wid * 16384;
#pragma unroll
  for (int q = 0; q < 4; ++q)
#pragma unroll
    for (int nf = 0; nf < 4; ++nf)
      *(f32x4v*)(reg + (q * 4 + nf) * 1024 + lane * 16) = acc[wk ? q : 4 + q][nf];
  __syncthreads();
  const char* preg = lds + (size_t)(wid ^ 1) * 16384;
#pragma unroll
  for (int q = 0; q < 4; ++q)
#pragma unroll
    for (int nf = 0; nf < 4; ++nf)
      ak[q][nf] = acc[wk ? 4 + q : q][nf] +
                  *(const f32x4v*)(preg + (q * 4 + nf) * 1024 + lane * 16);
  __syncthreads();
}

// ---------------- QKV GEMM + bias + RoPE (q pre-scaled by QSCALE); v -> VT ----------------
__global__ __launch_bounds__(512, 2) void gemm_qkv_kernel(
    const __hip_bfloat16* __restrict__ A, const __hip_bfloat16* __restrict__ BT,
    const float* __restrict__ bqkv, const float* __restrict__ ct, const float* __restrict__ st,
    __hip_bfloat16* __restrict__ qb, __hip_bfloat16* __restrict__ kb,
    __hip_bfloat16* __restrict__ vb) {
  __shared__ char lds[147456];
  const f32x4v fz = {0.f, 0.f, 0.f, 0.f};
  f32x4v acc[8][4];
#pragma unroll
  for (int mf = 0; mf < 8; ++mf)
#pragma unroll
    for (int nf = 0; nf < 4; ++nf) acc[mf][nf] = fz;
  int bx, by;
  xcd_swizzle(bx, by);
  const int brow = by * 256, bcol = bx * 128;
  gemm_core3((const char*)A, (const char*)BT, brow, bcol, lds, acc);

  const int tid = threadIdx.x, lane = tid & 63, wid = tid >> 6;
  const int g = lane >> 4, ln15 = lane & 15;
  const int wr = wid >> 2, wc = (wid >> 1) & 1, wk = wid & 1;
  f32x4v ak[4][4];
  kreduce(lds, acc, ak, wid, lane, wk);

  const int cb = bcol + wc * 64;
  const int which = cb >> 11;
  const int head = (cb & 2047) >> 6;
  const int rowbase = brow + wr * 128 + wk * 64;
  const int nidx = rowbase >> 11;
  const int posb = rowbase & 2047;
  float bias[4];
#pragma unroll
  for (int nf = 0; nf < 4; ++nf) bias[nf] = bqkv[cb + nf * 16 + ln15];

  if (which == 2) {
    char* tp = lds + wid * 8192;
    const size_t vhead = ((size_t)nidx * NHEADS + head) * (HDIM * SEQ);
#pragma unroll
    for (int q = 0; q < 4; ++q)
#pragma unroll
      for (int r = 0; r < 4; ++r) {
        const int posl = q * 16 + g * 4 + r;
#pragma unroll
        for (int nf = 0; nf < 4; ++nf) {
          const int d = nf * 16 + ln15;
          *(unsigned short*)(tp + d * 128 + ((posl * 2) ^ ((d & 7) << 4))) =
              f2bfu(ak[q][nf][r] + bias[nf]);
        }
      }
    asm volatile("s_waitcnt lgkmcnt(0)" ::: "memory");
    __builtin_amdgcn_sched_barrier(0);
#pragma unroll
    for (int i = 0; i < 8; ++i) {
      const int dl = i * 8 + (lane >> 3);
      const int cs = (lane & 7) ^ (dl & 7);
      const uint4 val = *(const uint4*)(tp + dl * 128 + cs * 16);
      *(uint4*)((char*)vb + (vhead + (size_t)dl * SEQ + posb + (lane & 7) * 8) * 2) = val;
    }
  } else {
    __hip_bfloat16* dst = (which == 0) ? qb : kb;
    const float qs = (which == 0) ? QSCALE : 1.0f;
    char* tp = lds + wid * 8192;
#pragma unroll
    for (int q = 0; q < 4; ++q)
#pragma unroll
      for (int r = 0; r < 4; ++r) {
        const int posl = q * 16 + g * 4 + r;
        const int pos = posb + posl;
        float v0 = ak[q][0][r] + bias[0];
        float v1 = ak[q][1][r] + bias[1];
        float v2 = ak[q][2][r] + bias[2];
        float v3 = ak[q][3][r] + bias[3];
        const float c0 = ct[pos * 16 + ln15], s0 = st[pos * 16 + ln15];
        const float x1 = v0, x2 = v1;
        v0 = (x1 * c0 - x2 * s0) * qs;
        v1 = (x2 * c0 + x1 * s0) * qs;
        v2 *= qs;
        v3 *= qs;
        const int sw2 = (posl & 7) << 4;
        char* rowp = tp + posl * 128;
        *(unsigned short*)(rowp + ((ln15 * 2) ^ sw2)) = f2bfu(v0);
        *(unsigned short*)(rowp + ((32 + ln15 * 2) ^ sw2)) = f2bfu(v1);
        *(unsigned short*)(rowp + ((64 + ln15 * 2) ^ sw2)) = f2bfu(v2);
        *(unsigned short*)(rowp + ((96 + ln15 * 2) ^ sw2)) = f2bfu(v3);
      }
    asm volatile("s_waitcnt lgkmcnt(0)" ::: "memory");
    __builtin_amdgcn_sched_barrier(0);
    const size_t qkbase = (((size_t)(nidx * NHEADS + head)) * SEQ + posb) * HDIM;
#pragma unroll
    for (int i = 0; i < 8; ++i) {
      const int rr = i * 8 + (lane >> 3);
      const int cs = (lane & 7) ^ (rr & 7);
      const uint4 val = *(const uint4*)(tp + rr * 128 + cs * 16);
      *(uint4*)((char*)dst + (qkbase + (size_t)rr * HDIM) * 2 + (lane & 7) * 16) = val;
    }
  }
}

// ---------------- out-proj GEMM + bias + residual -> f32 out (LDS-repacked) ----------
__global__ __launch_bounds__(512, 2) void gemm_out_kernel(
    const __hip_bfloat16* __restrict__ A, const __hip_bfloat16* __restrict__ BT,
    const float* __restrict__ bout, const float* __restrict__ skip,
    float* __restrict__ out) {
  __shared__ char lds[147456];
  const f32x4v fz = {0.f, 0.f, 0.f, 0.f};
  f32x4v acc[8][4];
#pragma unroll
  for (int mf = 0; mf < 8; ++mf)
#pragma unroll
    for (int nf = 0; nf < 4; ++nf) acc[mf][nf] = fz;
  int bx, by;
  xcd_swizzle(bx, by);
  const int brow = by * 256, bcol = bx * 128;
  gemm_core3((const char*)A, (const char*)BT, brow, bcol, lds, acc);

  const int tid = threadIdx.x, lane = tid & 63, wid = tid >> 6;
  const int g = lane >> 4, ln15 = lane & 15;
  const int wr = wid >> 2, wc = (wid >> 1) & 1, wk = wid & 1;
  f32x4v ak[4][4];
  kreduce(lds, acc, ak, wid, lane, wk);

  const int rowbase = brow + wr * 128 + wk * 64;
  char* tp = lds + wid * 16384;
#pragma unroll
  for (int q = 0; q < 4; ++q)
#pragma unroll
    for (int r = 0; r < 4; ++r) {
      const int posl = q * 16 + g * 4 + r;
      const int sw2 = ((posl >> 2) & 3) << 6;
      char* rowp = tp + posl * 256;
#pragma unroll
      for (int nf = 0; nf < 4; ++nf)
        *(float*)(rowp + ((nf * 64 + ln15 * 4) ^ sw2)) = ak[q][nf][r];
    }
  asm volatile("s_waitcnt lgkmcnt(0)" ::: "memory");
  __builtin_amdgcn_sched_barrier(0);
  const int colb = bcol + wc * 64;
#pragma unroll
  for (int i = 0; i < 16; ++i) {
    const int rr = i * 4 + (lane >> 4);
    const int cp = lane & 15;
    const float4 a4 = *(const float4*)(tp + rr * 256 + cp * 16);
    const int lc = (cp * 16) ^ (((rr >> 2) & 3) << 6);
    const int col = colb + (lc >> 2);
    const int row = rowbase + rr;
    const float4 sk = *(const float4*)(skip + (size_t)row * DIMM + col);
    const float4 bo = *(const float4*)(bout + col);
    float4 o4;
    o4.x = a4.x + sk.x + bo.x;
    o4.y = a4.y + sk.y + bo.y;
    o4.z = a4.z + sk.z + bo.z;
    o4.w = a4.w + sk.w + bo.w;
    *(float4*)(out + (size_t)row * DIMM + col) = o4;
  }
}

// ---------------- causal flash attention: ring-3 KV, exp2 softmax (R10/R11 proven) ------
__global__ __launch_bounds__(256) void attn_kernel(
    const __hip_bfloat16* __restrict__ qb, const __hip_bfloat16* __restrict__ kb,
    const __hip_bfloat16* __restrict__ vtb, __hip_bfloat16* __restrict__ ob) {
  __shared__ char sm[49664];
  float* lred = (float*)(sm + 49152);
  const int tid = threadIdx.x, lane = tid & 63, wid = tid >> 6;
  const int ln31 = lane & 31, hi = lane >> 5;
  const int head = blockIdx.x;
  const int qbi = (int)gridDim.y - 1 - (int)blockIdx.y;  // heavy blocks dispatch first
  const size_t hb = (size_t)head * (SEQ * HDIM);
  const int q0 = qbi * 128;
  const int qw = q0 + wid * 32;
  const int qg = qw + ln31;
  const int nt = qbi * 2 + 2;
  const char* Kg = (const char*)(kb + hb);
  const char* Vg = (const char*)(vtb + hb);

  bfv8 qf[4];
  {
    const char* Qp = (const char*)(qb + hb) + (size_t)(qw + ln31) * 128 + hi * 16;
#pragma unroll
    for (int j = 0; j < 4; ++j) qf[j] = *(const bfv8*)(Qp + j * 32);
  }

  f32x16 o0, o1;
#pragma unroll
  for (int i = 0; i < 16; ++i) { o0[i] = 0.f; o1[i] = 0.f; }
  float m_run = -1e30f, l_run = 0.f;
  const int swz = (ln31 & 7) << 4;

#define ATTN_STAGE(T, B)                                                            \
  {                                                                                 \
    const int kvs = (T)*64;                                                         \
    _Pragma("unroll") for (int i = 0; i < 2; ++i) {                                 \
      const int f = (tid + i * 256) * 16;                                           \
      const int row = f >> 7;                                                       \
      const int src = (f & 127) ^ ((row & 7) << 4);                                 \
      gload16(Kg + (size_t)(kvs + row) * 128 + src, sm + (B)*8192 + f);             \
      gload16(Vg + (size_t)row * 4096 + (size_t)kvs * 2 + src,                      \
              sm + 24576 + (B)*8192 + f);                                           \
    }                                                                               \
  }

  ATTN_STAGE(0, 0);
  if (nt > 1) ATTN_STAGE(1, 1);
  asm volatile("s_waitcnt vmcnt(4)" ::: "memory");
  __builtin_amdgcn_s_barrier();

  for (int t = 0; t < nt; ++t) {
    const int kvb = t * 64;
    const bool st = (t + 2 < nt);
    if (st) ATTN_STAGE(t + 2, (t + 2) % 3);
    if (kvb <= qw + 31) {
      const char* ldsK = sm + (t % 3) * 8192;
      const char* ldsV = sm + 24576 + (t % 3) * 8192;
      f32x16 s0, s1;
#pragma unroll
      for (int i = 0; i < 16; ++i) { s0[i] = 0.f; s1[i] = 0.f; }
      __builtin_amdgcn_s_setprio(1);
#pragma unroll
      for (int j = 0; j < 4; ++j) {
        const int byt = j * 32 + hi * 16;
        const bfv8 k0 = *(const bfv8*)(ldsK + ln31 * 128 + (byt ^ swz));
        const bfv8 k1 = *(const bfv8*)(ldsK + (32 + ln31) * 128 + (byt ^ swz));
        s0 = mfma32(k0, qf[j], s0);
        s1 = mfma32(k1, qf[j], s1);
      }
      __builtin_amdgcn_s_setprio(0);
      float p[32];
#pragma unroll
      for (int r = 0; r < 16; ++r) { p[r] = s0[r]; p[16 + r] = s1[r]; }
      if (kvb + 63 > qw) {
#pragma unroll
        for (int r = 0; r < 16; ++r) {
          const int kvo = (r & 3) + 8 * (r >> 2) + 4 * hi;
          if (kvb + kvo > qg) p[r] = -1e30f;
          if (kvb + 32 + kvo > qg) p[16 + r] = -1e30f;
        }
      }
      // balanced tree max (depth ~6, was 31-deep serial chain)
      float m16[16];
#pragma unroll
      for (int r = 0; r < 16; ++r) m16[r] = fmaxf(p[r], p[16 + r]);
#pragma unroll
      for (int w2 = 8; w2 >= 1; w2 >>= 1)
#pragma unroll
        for (int r = 0; r < w2; ++r) m16[r] = fmaxf(m16[r], m16[r + w2]);
      float mx = m16[0];
      mx = fmaxf(mx, __shfl_xor(mx, 32));
      if (!__all(mx <= m_run + 8.0f)) {  // defer-max: P bounded by 2^8
        const float mn = fmaxf(m_run, mx);
        const float al = __builtin_amdgcn_exp2f(m_run - mn);
        m_run = mn;
        l_run *= al;
        lred[wid * 32 + ln31] = al;
        asm volatile("s_waitcnt lgkmcnt(0)" ::: "memory");
        __builtin_amdgcn_sched_barrier(0);
#pragma unroll
        for (int r = 0; r < 16; ++r) {
          const float a = lred[wid * 32 + (r & 3) + 8 * (r >> 2) + 4 * hi];
          o0[r] *= a;
          o1[r] *= a;
        }
      }
      float ps = 0.f;
#pragma unroll
      for (int r = 0; r < 32; ++r) {
        p[r] = __builtin_amdgcn_exp2f(p[r] - m_run);
        ps += p[r];
      }
      ps += __shfl_xor(ps, 32);
      l_run += ps;
      unsigned c[16];
#pragma unroll
      for (int i = 0; i < 16; ++i) c[i] = pack2bf(p[2 * i], p[2 * i + 1]);
      bfv8 paf[4];
#pragma unroll
      for (int fI = 0; fI < 4; ++fI) {
        unsigned a0 = c[fI * 4 + 0], b0 = c[fI * 4 + 2];
        unsigned a1 = c[fI * 4 + 1], b1 = c[fI * 4 + 3];
        swap32(a0, b0, hi);
        swap32(a1, b1, hi);
        union { unsigned u[4]; bfv8 v; } w;
        w.u[0] = a0; w.u[1] = a1; w.u[2] = b0; w.u[3] = b1;
        paf[fI] = w.v;
      }
      __builtin_amdgcn_s_setprio(1);
#pragma unroll
      for (int ss = 0; ss < 4; ++ss) {
        const int byt = ss * 32 + hi * 16;
        const bfv8 v0 = *(const bfv8*)(ldsV + ln31 * 128 + (byt ^ swz));
        const bfv8 v1 = *(const bfv8*)(ldsV + (32 + ln31) * 128 + (byt ^ swz));
        o0 = mfma32(paf[ss], v0, o0);
        o1 = mfma32(paf[ss], v1, o1);
      }
      __builtin_amdgcn_s_setprio(0);
    }
    if (st) {
      asm volatile("s_waitcnt vmcnt(4)" ::: "memory");
    } else if (t + 1 < nt) {
      asm volatile("s_waitcnt vmcnt(0)" ::: "memory");
    }
    asm volatile("" ::: "memory");
    __builtin_amdgcn_s_barrier();
  }
#undef ATTN_STAGE

  lred[wid * 32 + ln31] = l_run;
  asm volatile("s_waitcnt lgkmcnt(0)" ::: "memory");
  __builtin_amdgcn_sched_barrier(0);
  const int nidx = head >> 5, hh = head & 31;
#pragma unroll
  for (int r = 0; r < 16; ++r) {
    const int qrow = qw + (r & 3) + 8 * (r >> 2) + 4 * hi;
    const float inv = 1.0f / lred[wid * 32 + (r & 3) + 8 * (r >> 2) + 4 * hi];
    __hip_bfloat16* dst = ob + ((size_t)nidx * SEQ + qrow) * DIMM + hh * 64;
    dst[ln31] = __float2bfloat16(o0[r] * inv);
    dst[32 + ln31] = __float2bfloat16(o1[r] * inv);
  }
}

extern "C" void kernel_launch(void* const* d_in, const int* in_sizes, int n_in,
                              void* d_out, int out_size, void* d_ws, size_t ws_size,
                              hipStream_t stream) {
  const float* x = (const float*)d_in[0];
  const float* ln_w = (const float*)d_in[1];
  const float* ln_b = (const float*)d_in[2];
  const float* w_qkv = (const float*)d_in[3];
  const float* b_qkv = (const float*)d_in[4];
  const float* w_out = (const float*)d_in[5];
  const float* b_out = (const float*)d_in[6];
  float* out = (float*)d_out;

  char* ws = (char*)d_ws;
  size_t off = 0;
  auto alloc = [&](size_t bytes) -> char* {
    char* p = ws + off;
    off += (bytes + 255) & ~(size_t)255;
    return p;
  };
  __hip_bfloat16* h = (__hip_bfloat16*)alloc((size_t)ROWS * DIMM * 2);
  __hip_bfloat16* wqkvT = (__hip_bfloat16*)alloc((size_t)3 * DIMM * DIMM * 2);
  __hip_bfloat16* woutT = (__hip_bfloat16*)alloc((size_t)DIMM * DIMM * 2);
  __hip_bfloat16* qbuf = (__hip_bfloat16*)alloc((size_t)ROWS * DIMM * 2);
  __hip_bfloat16* kbuf = (__hip_bfloat16*)alloc((size_t)ROWS * DIMM * 2);
  __hip_bfloat16* vtbuf = (__hip_bfloat16*)alloc((size_t)ROWS * DIMM * 2);
  __hip_bfloat16* obuf = (__hip_bfloat16*)alloc((size_t)ROWS * DIMM * 2);
  float* ct = (float*)alloc((size_t)SEQ * NFREQ * 4);
  float* st = (float*)alloc((size_t)SEQ * NFREQ * 4);

  prep_kernel<<<dim3(PB_TOTAL), dim3(256), 0, stream>>>(
      x, ln_w, ln_b, h, w_qkv, wqkvT, w_out, woutT, ct, st);
  gemm_qkv_kernel<<<dim3(3 * DIMM / 128, ROWS / 256), dim3(512), 0, stream>>>(
      h, wqkvT, b_qkv, ct, st, qbuf, kbuf, vtbuf);
  attn_kernel<<<dim3(NBATCH * NHEADS, SEQ / 128), dim3(256), 0, stream>>>(
      qbuf, kbuf, vtbuf, obuf);
  gemm_out_kernel<<<dim3(DIMM / 128, ROWS / 256), dim3(512), 0, stream>>>(
      obuf, woutT, b_out, x, out);
}

// Round 14
// 254.153 us; speedup vs baseline: 1.1578x; 1.0353x over previous
//
#include <hip/hip_runtime.h>
#include <hip/hip_bf16.h>
#include <cstdint>
#include <cstddef>

#define DIMM 2048
#define NHEADS 32
#define HDIM 64
#define SEQ 2048
#define NBATCH 2
#define ROWS 4096
#define NFREQ 16
#define NKT3 32  // K=2048 / BK=64
#define QSCALE 0.1803368802f  // 0.125 * log2(e): folded into q -> softmax in exp2 domain

// prep_kernel block ranges
#define PB_LN ROWS                           // 4096
#define PB_TQKV (192 * 64)                   // 12288
#define PB_TOUT (64 * 64)                    // 4096
#define PB_ROPE ((SEQ * NFREQ + 255) / 256)  // 128
#define PB_TOTAL (PB_LN + PB_TQKV + PB_TOUT + PB_ROPE)

typedef __bf16 bfv8 __attribute__((ext_vector_type(8)));
typedef float f32x4v __attribute__((ext_vector_type(4)));
typedef float f32x16 __attribute__((ext_vector_type(16)));

__device__ __forceinline__ void gload16(const void* g, void* l) {
  __builtin_amdgcn_global_load_lds((const __attribute__((address_space(1))) void*)g,
                                   (__attribute__((address_space(3))) void*)l, 16, 0, 0);
}

__device__ __forceinline__ f32x4v mfma16(bfv8 a, bfv8 b, f32x4v c) {
  return __builtin_amdgcn_mfma_f32_16x16x32_bf16(a, b, c, 0, 0, 0);
}

__device__ __forceinline__ f32x16 mfma32(bfv8 a, bfv8 b, f32x16 c) {
  return __builtin_amdgcn_mfma_f32_32x32x16_bf16(a, b, c, 0, 0, 0);
}

__device__ __forceinline__ unsigned short f2bfu(float f) {
  __hip_bfloat16 h = __float2bfloat16(f);
  return __builtin_bit_cast(unsigned short, h);
}

__device__ __forceinline__ void swap32(unsigned& a, unsigned& b, const int hi) {
  const unsigned ta = (unsigned)__shfl_xor((int)a, 32);
  const unsigned tb = (unsigned)__shfl_xor((int)b, 32);
  const unsigned na = hi ? tb : a;
  const unsigned nb = hi ? b : ta;
  a = na;
  b = nb;
}

__device__ __forceinline__ void xcd_swizzle(int& bx, int& by) {
  const int gx = gridDim.x, nwg = gx * gridDim.y;
  const int orig = blockIdx.y * gx + blockIdx.x;
  const int q = nwg >> 3, r = nwg & 7;
  const int xcd = orig & 7, loc = orig >> 3;
  const int wg = (xcd < r ? xcd * (q + 1) : r * (q + 1) + (xcd - r) * q) + loc;
  bx = wg % gx;
  by = wg / gx;
}

// ---------------- fused prep: LN | transpose(w_qkv) | transpose(w_out) | rope ----------
__device__ __forceinline__ void transpose32_body(const float* __restrict__ W,
                                                 __hip_bfloat16* __restrict__ WT,
                                                 int K, int N, int n0, int k0,
                                                 float* tile /*[32][33]*/) {
  const int tid = threadIdx.x;
  const int tx = tid & 31, ty = tid >> 5;
#pragma unroll
  for (int j = 0; j < 4; ++j)
    tile[(ty + j * 8) * 33 + tx] = W[(size_t)(k0 + ty + j * 8) * N + n0 + tx];
  __syncthreads();
#pragma unroll
  for (int j = 0; j < 4; ++j)
    WT[(size_t)(n0 + ty + j * 8) * K + k0 + tx] = __float2bfloat16(tile[tx * 33 + ty + j * 8]);
}

__global__ __launch_bounds__(256) void prep_kernel(
    const float* __restrict__ x, const float* __restrict__ lw, const float* __restrict__ lb,
    __hip_bfloat16* __restrict__ h, const float* __restrict__ w_qkv,
    __hip_bfloat16* __restrict__ wqkvT, const float* __restrict__ w_out,
    __hip_bfloat16* __restrict__ woutT, float* __restrict__ ct, float* __restrict__ st) {
  __shared__ float pls[32 * 33];
  const int b = blockIdx.x;
  const int t = threadIdx.x;
  if (b < PB_LN) {
    const int row = b;
    const float4* xr = (const float4*)(x + (size_t)row * DIMM);
    float4 a = xr[t * 2], bb4 = xr[t * 2 + 1];
    float e[8];
    *(float4*)e = a; *(float4*)(e + 4) = bb4;
    float s = 0.f, ss = 0.f;
#pragma unroll
    for (int j = 0; j < 8; ++j) { s += e[j]; ss += e[j] * e[j]; }
#pragma unroll
    for (int o = 1; o < 64; o <<= 1) { s += __shfl_xor(s, o); ss += __shfl_xor(ss, o); }
    float* red = pls;
    const int wid = t >> 6;
    if ((t & 63) == 0) { red[wid * 2] = s; red[wid * 2 + 1] = ss; }
    __syncthreads();
    s = red[0] + red[2] + red[4] + red[6];
    ss = red[1] + red[3] + red[5] + red[7];
    const float mu = s * (1.f / DIMM);
    const float var = ss * (1.f / DIMM) - mu * mu;
    const float rs = rsqrtf(var + 1e-5f);
    const float4* w4 = (const float4*)lw;
    const float4* b4 = (const float4*)lb;
    float4 wa = w4[t * 2], wb = w4[t * 2 + 1], ba = b4[t * 2], bb = b4[t * 2 + 1];
    float wv[8], bv[8];
    *(float4*)wv = wa; *(float4*)(wv + 4) = wb;
    *(float4*)bv = ba; *(float4*)(bv + 4) = bb;
    unsigned short hv[8];
#pragma unroll
    for (int j = 0; j < 8; ++j)
      hv[j] = f2bfu((e[j] - mu) * rs * wv[j] + bv[j]);
    *(uint4*)((char*)h + (size_t)row * (DIMM * 2) + t * 16) = *(uint4*)hv;
  } else if (b < PB_LN + PB_TQKV) {
    const int i = b - PB_LN;
    const int n0 = (i % 192) * 32, k0 = (i / 192) * 32;
    transpose32_body(w_qkv, wqkvT, DIMM, 3 * DIMM, n0, k0, pls);
  } else if (b < PB_LN + PB_TQKV + PB_TOUT) {
    const int i = b - PB_LN - PB_TQKV;
    const int n0 = (i % 64) * 32, k0 = (i / 64) * 32;
    transpose32_body(w_out, woutT, DIMM, DIMM, n0, k0, pls);
  } else {
    const int i = (b - PB_LN - PB_TQKV - PB_TOUT) * 256 + t;
    if (i < SEQ * NFREQ) {
      const int pos = i >> 4, f = i & 15;
      const float freq = powf(10000.0f, -(float)f / 16.0f);
      const float ang = (float)pos * freq;
      ct[i] = cosf(ang);
      st[i] = sinf(ang);
    }
  }
}

// ======== 256x128xK GEMM, BK=64, 8 waves = 2M x 2N x 2K, ring-3 LDS (R7, proven) ========
__device__ __forceinline__ void stageA64(const char* Ab, int brow, int kt,
                                         char* bufA, int c, int lane) {
  const int row = c * 8 + (lane >> 3);
  const int src = ((lane & 7) * 16) ^ ((row & 7) << 4);
  gload16(Ab + (size_t)(brow + row) * 4096 + kt * 128 + src, bufA + c * 1024);
}
__device__ __forceinline__ void stageB64(const char* Bb, int bcol, int kt,
                                         char* bufB, int c, int lane) {
  const int row = c * 8 + (lane >> 3);
  const int src = ((lane & 7) * 16) ^ ((row & 7) << 4);
  gload16(Bb + (size_t)(bcol + row) * 4096 + kt * 128 + src, bufB + c * 1024);
}

__device__ __forceinline__ void gemm_core3(const char* Ab, const char* Bb,
                                           int brow, int bcol, char* lds,
                                           f32x4v acc[8][4]) {
  const int tid = threadIdx.x, lane = tid & 63, wid = tid >> 6;
  const int g = lane >> 4, ln15 = lane & 15;
  const int wr = wid >> 2, wc = (wid >> 1) & 1, wk = wid & 1;
  const int kb = wk * 64;
#pragma unroll
  for (int t = 0; t < 2; ++t) {
    char* bufA = lds + t * 49152;
    char* bufB = bufA + 32768;
    stageA64(Ab, brow, t, bufA, wid, lane);
    stageA64(Ab, brow, t, bufA, wid + 8, lane);
    stageA64(Ab, brow, t, bufA, wid + 16, lane);
    stageA64(Ab, brow, t, bufA, wid + 24, lane);
    stageB64(Bb, bcol, t, bufB, wid, lane);
    stageB64(Bb, bcol, t, bufB, wid + 8, lane);
  }
  asm volatile("s_waitcnt vmcnt(6)" ::: "memory");
  __builtin_amdgcn_s_barrier();

  for (int t = 0; t < NKT3; ++t) {
    char* bufA = lds + (t % 3) * 49152;
    char* bufB = bufA + 32768;
    char* nbufA = lds + ((t + 2) % 3) * 49152;
    char* nbufB = nbufA + 32768;
    const bool st = (t + 2 < NKT3);
    bfv8 af[4], bfr[4];
#pragma unroll
    for (int mi = 0; mi < 4; ++mi) {
      const int ra = wr * 128 + mi * 16 + ln15;
      af[mi] = *(const bfv8*)(bufA + (size_t)ra * 128 + ((kb + g * 16) ^ ((ra & 7) << 4)));
    }
#pragma unroll
    for (int nf = 0; nf < 4; ++nf) {
      const int rb = wc * 64 + nf * 16 + ln15;
      bfr[nf] = *(const bfv8*)(bufB + (size_t)rb * 128 + ((kb + g * 16) ^ ((rb & 7) << 4)));
    }
    if (st) {
      stageA64(Ab, brow, t + 2, nbufA, wid, lane);
      stageA64(Ab, brow, t + 2, nbufA, wid + 8, lane);
      stageB64(Bb, bcol, t + 2, nbufB, wid, lane);
    }
    __builtin_amdgcn_s_setprio(1);
#pragma unroll
    for (int mi = 0; mi < 4; ++mi)
#pragma unroll
      for (int nf = 0; nf < 4; ++nf)
        acc[mi][nf] = mfma16(af[mi], bfr[nf], acc[mi][nf]);
    __builtin_amdgcn_s_setprio(0);
    bfv8 ao[4];
#pragma unroll
    for (int mi = 0; mi < 4; ++mi) {
      const int ra = wr * 128 + (4 + mi) * 16 + ln15;
      ao[mi] = *(const bfv8*)(bufA + (size_t)ra * 128 + ((kb + g * 16) ^ ((ra & 7) << 4)));
    }
    if (st) {
      stageA64(Ab, brow, t + 2, nbufA, wid + 16, lane);
      stageA64(Ab, brow, t + 2, nbufA, wid + 24, lane);
      stageB64(Bb, bcol, t + 2, nbufB, wid + 8, lane);
    }
    __builtin_amdgcn_s_setprio(1);
#pragma unroll
    for (int mi = 0; mi < 4; ++mi)
#pragma unroll
      for (int nf = 0; nf < 4; ++nf)
        acc[4 + mi][nf] = mfma16(ao[mi], bfr[nf], acc[4 + mi][nf]);
    __builtin_amdgcn_s_setprio(0);
    if (st) {
      asm volatile("s_waitcnt vmcnt(6)" ::: "memory");
    } else if (t == NKT3 - 2) {
      asm volatile("s_waitcnt vmcnt(0)" ::: "memory");
    }
    asm volatile("" ::: "memory");
    __builtin_amdgcn_s_barrier();
  }
}

__device__ __forceinline__ void kreduce(char* lds, f32x4v acc[8][4], f32x4v ak[4][4],
                                        int wid, int lane, int wk) {
  char* reg = lds + (size_t)wid * 16384;
#pragma unroll
  for (int q = 0; q < 4; ++q)
#pragma unroll
    for (int nf = 0; nf < 4; ++nf)
      *(f32x4v*)(reg + (q * 4 + nf) * 1024 + lane * 16) = acc[wk ? q : 4 + q][nf];
  __syncthreads();
  const char* preg = lds + (size_t)(wid ^ 1) * 16384;
#pragma unroll
  for (int q = 0; q < 4; ++q)
#pragma unroll
    for (int nf = 0; nf < 4; ++nf)
      ak[q][nf] = acc[wk ? 4 + q : q][nf] +
                  *(const f32x4v*)(preg + (q * 4 + nf) * 1024 + lane * 16);
  __syncthreads();
}

// ---------------- QKV GEMM + bias + RoPE (q pre-scaled by QSCALE); v -> VT ----------------
__global__ __launch_bounds__(512, 2) void gemm_qkv_kernel(
    const __hip_bfloat16* __restrict__ A, const __hip_bfloat16* __restrict__ BT,
    const float* __restrict__ bqkv, const float* __restrict__ ct, const float* __restrict__ st,
    __hip_bfloat16* __restrict__ qb, __hip_bfloat16* __restrict__ kb,
    __hip_bfloat16* __restrict__ vb) {
  __shared__ char lds[147456];
  const f32x4v fz = {0.f, 0.f, 0.f, 0.f};
  f32x4v acc[8][4];
#pragma unroll
  for (int mf = 0; mf < 8; ++mf)
#pragma unroll
    for (int nf = 0; nf < 4; ++nf) acc[mf][nf] = fz;
  int bx, by;
  xcd_swizzle(bx, by);
  const int brow = by * 256, bcol = bx * 128;
  gemm_core3((const char*)A, (const char*)BT, brow, bcol, lds, acc);

  const int tid = threadIdx.x, lane = tid & 63, wid = tid >> 6;
  const int g = lane >> 4, ln15 = lane & 15;
  const int wr = wid >> 2, wc = (wid >> 1) & 1, wk = wid & 1;
  f32x4v ak[4][4];
  kreduce(lds, acc, ak, wid, lane, wk);

  const int cb = bcol + wc * 64;
  const int which = cb >> 11;
  const int head = (cb & 2047) >> 6;
  const int rowbase = brow + wr * 128 + wk * 64;
  const int nidx = rowbase >> 11;
  const int posb = rowbase & 2047;
  float bias[4];
#pragma unroll
  for (int nf = 0; nf < 4; ++nf) bias[nf] = bqkv[cb + nf * 16 + ln15];

  if (which == 2) {
    char* tp = lds + wid * 8192;
    const size_t vhead = ((size_t)nidx * NHEADS + head) * (HDIM * SEQ);
#pragma unroll
    for (int q = 0; q < 4; ++q)
#pragma unroll
      for (int r = 0; r < 4; ++r) {
        const int posl = q * 16 + g * 4 + r;
#pragma unroll
        for (int nf = 0; nf < 4; ++nf) {
          const int d = nf * 16 + ln15;
          *(unsigned short*)(tp + d * 128 + ((posl * 2) ^ ((d & 7) << 4))) =
              f2bfu(ak[q][nf][r] + bias[nf]);
        }
      }
    asm volatile("s_waitcnt lgkmcnt(0)" ::: "memory");
    __builtin_amdgcn_sched_barrier(0);
#pragma unroll
    for (int i = 0; i < 8; ++i) {
      const int dl = i * 8 + (lane >> 3);
      const int cs = (lane & 7) ^ (dl & 7);
      const uint4 val = *(const uint4*)(tp + dl * 128 + cs * 16);
      *(uint4*)((char*)vb + (vhead + (size_t)dl * SEQ + posb + (lane & 7) * 8) * 2) = val;
    }
  } else {
    __hip_bfloat16* dst = (which == 0) ? qb : kb;
    const float qs = (which == 0) ? QSCALE : 1.0f;
    char* tp = lds + wid * 8192;
#pragma unroll
    for (int q = 0; q < 4; ++q)
#pragma unroll
      for (int r = 0; r < 4; ++r) {
        const int posl = q * 16 + g * 4 + r;
        const int pos = posb + posl;
        float v0 = ak[q][0][r] + bias[0];
        float v1 = ak[q][1][r] + bias[1];
        float v2 = ak[q][2][r] + bias[2];
        float v3 = ak[q][3][r] + bias[3];
        const float c0 = ct[pos * 16 + ln15], s0 = st[pos * 16 + ln15];
        const float x1 = v0, x2 = v1;
        v0 = (x1 * c0 - x2 * s0) * qs;
        v1 = (x2 * c0 + x1 * s0) * qs;
        v2 *= qs;
        v3 *= qs;
        const int sw2 = (posl & 7) << 4;
        char* rowp = tp + posl * 128;
        *(unsigned short*)(rowp + ((ln15 * 2) ^ sw2)) = f2bfu(v0);
        *(unsigned short*)(rowp + ((32 + ln15 * 2) ^ sw2)) = f2bfu(v1);
        *(unsigned short*)(rowp + ((64 + ln15 * 2) ^ sw2)) = f2bfu(v2);
        *(unsigned short*)(rowp + ((96 + ln15 * 2) ^ sw2)) = f2bfu(v3);
      }
    asm volatile("s_waitcnt lgkmcnt(0)" ::: "memory");
    __builtin_amdgcn_sched_barrier(0);
    const size_t qkbase = (((size_t)(nidx * NHEADS + head)) * SEQ + posb) * HDIM;
#pragma unroll
    for (int i = 0; i < 8; ++i) {
      const int rr = i * 8 + (lane >> 3);
      const int cs = (lane & 7) ^ (rr & 7);
      const uint4 val = *(const uint4*)(tp + rr * 128 + cs * 16);
      *(uint4*)((char*)dst + (qkbase + (size_t)rr * HDIM) * 2 + (lane & 7) * 16) = val;
    }
  }
}

// ---------------- out-proj GEMM + bias + residual -> f32 out (LDS-repacked) ----------
__global__ __launch_bounds__(512, 2) void gemm_out_kernel(
    const __hip_bfloat16* __restrict__ A, const __hip_bfloat16* __restrict__ BT,
    const float* __restrict__ bout, const float* __restrict__ skip,
    float* __restrict__ out) {
  __shared__ char lds[147456];
  const f32x4v fz = {0.f, 0.f, 0.f, 0.f};
  f32x4v acc[8][4];
#pragma unroll
  for (int mf = 0; mf < 8; ++mf)
#pragma unroll
    for (int nf = 0; nf < 4; ++nf) acc[mf][nf] = fz;
  int bx, by;
  xcd_swizzle(bx, by);
  const int brow = by * 256, bcol = bx * 128;
  gemm_core3((const char*)A, (const char*)BT, brow, bcol, lds, acc);

  const int tid = threadIdx.x, lane = tid & 63, wid = tid >> 6;
  const int g = lane >> 4, ln15 = lane & 15;
  const int wr = wid >> 2, wc = (wid >> 1) & 1, wk = wid & 1;
  f32x4v ak[4][4];
  kreduce(lds, acc, ak, wid, lane, wk);

  const int rowbase = brow + wr * 128 + wk * 64;
  char* tp = lds + wid * 16384;
#pragma unroll
  for (int q = 0; q < 4; ++q)
#pragma unroll
    for (int r = 0; r < 4; ++r) {
      const int posl = q * 16 + g * 4 + r;
      const int sw2 = ((posl >> 2) & 3) << 6;
      char* rowp = tp + posl * 256;
#pragma unroll
      for (int nf = 0; nf < 4; ++nf)
        *(float*)(rowp + ((nf * 64 + ln15 * 4) ^ sw2)) = ak[q][nf][r];
    }
  asm volatile("s_waitcnt lgkmcnt(0)" ::: "memory");
  __builtin_amdgcn_sched_barrier(0);
  const int colb = bcol + wc * 64;
#pragma unroll
  for (int i = 0; i < 16; ++i) {
    const int rr = i * 4 + (lane >> 4);
    const int cp = lane & 15;
    const float4 a4 = *(const float4*)(tp + rr * 256 + cp * 16);
    const int lc = (cp * 16) ^ (((rr >> 2) & 3) << 6);
    const int col = colb + (lc >> 2);
    const int row = rowbase + rr;
    const float4 sk = *(const float4*)(skip + (size_t)row * DIMM + col);
    const float4 bo = *(const float4*)(bout + col);
    float4 o4;
    o4.x = a4.x + sk.x + bo.x;
    o4.y = a4.y + sk.y + bo.y;
    o4.z = a4.z + sk.z + bo.z;
    o4.w = a4.w + sk.w + bo.w;
    *(float4*)(out + (size_t)row * DIMM + col) = o4;
  }
}

// ---------------- causal flash attention: ring-3 KV, exp2 softmax, cvt_pk pack ----------
__global__ __launch_bounds__(256) void attn_kernel(
    const __hip_bfloat16* __restrict__ qb, const __hip_bfloat16* __restrict__ kb,
    const __hip_bfloat16* __restrict__ vtb, __hip_bfloat16* __restrict__ ob) {
  __shared__ char sm[49664];
  float* lred = (float*)(sm + 49152);
  const int tid = threadIdx.x, lane = tid & 63, wid = tid >> 6;
  const int ln31 = lane & 31, hi = lane >> 5;
  const int head = blockIdx.x;
  const int qbi = (int)gridDim.y - 1 - (int)blockIdx.y;  // heavy blocks dispatch first
  const size_t hb = (size_t)head * (SEQ * HDIM);
  const int q0 = qbi * 128;
  const int qw = q0 + wid * 32;
  const int qg = qw + ln31;
  const int nt = qbi * 2 + 2;
  const char* Kg = (const char*)(kb + hb);
  const char* Vg = (const char*)(vtb + hb);

  bfv8 qf[4];
  {
    const char* Qp = (const char*)(qb + hb) + (size_t)(qw + ln31) * 128 + hi * 16;
#pragma unroll
    for (int j = 0; j < 4; ++j) qf[j] = *(const bfv8*)(Qp + j * 32);
  }

  f32x16 o0, o1;
#pragma unroll
  for (int i = 0; i < 16; ++i) { o0[i] = 0.f; o1[i] = 0.f; }
  float m_run = -1e30f, l_run = 0.f;
  const int swz = (ln31 & 7) << 4;

#define ATTN_STAGE(T, B)                                                            \
  {                                                                                 \
    const int kvs = (T)*64;                                                         \
    _Pragma("unroll") for (int i = 0; i < 2; ++i) {                                 \
      const int f = (tid + i * 256) * 16;                                           \
      const int row = f >> 7;                                                       \
      const int src = (f & 127) ^ ((row & 7) << 4);                                 \
      gload16(Kg + (size_t)(kvs + row) * 128 + src, sm + (B)*8192 + f);             \
      gload16(Vg + (size_t)row * 4096 + (size_t)kvs * 2 + src,                      \
              sm + 24576 + (B)*8192 + f);                                           \
    }                                                                               \
  }

  ATTN_STAGE(0, 0);
  if (nt > 1) ATTN_STAGE(1, 1);
  asm volatile("s_waitcnt vmcnt(4)" ::: "memory");
  __builtin_amdgcn_s_barrier();

  for (int t = 0; t < nt; ++t) {
    const int kvb = t * 64;
    const bool st = (t + 2 < nt);
    if (st) ATTN_STAGE(t + 2, (t + 2) % 3);
    if (kvb <= qw + 31) {
      const char* ldsK = sm + (t % 3) * 8192;
      const char* ldsV = sm + 24576 + (t % 3) * 8192;
      f32x16 s0, s1;
#pragma unroll
      for (int i = 0; i < 16; ++i) { s0[i] = 0.f; s1[i] = 0.f; }
      __builtin_amdgcn_s_setprio(1);
#pragma unroll
      for (int j = 0; j < 4; ++j) {
        const int byt = j * 32 + hi * 16;
        const bfv8 k0 = *(const bfv8*)(ldsK + ln31 * 128 + (byt ^ swz));
        const bfv8 k1 = *(const bfv8*)(ldsK + (32 + ln31) * 128 + (byt ^ swz));
        s0 = mfma32(k0, qf[j], s0);
        s1 = mfma32(k1, qf[j], s1);
      }
      __builtin_amdgcn_s_setprio(0);
      float p[32];
#pragma unroll
      for (int r = 0; r < 16; ++r) { p[r] = s0[r]; p[16 + r] = s1[r]; }
      if (kvb + 63 > qw) {
#pragma unroll
        for (int r = 0; r < 16; ++r) {
          const int kvo = (r & 3) + 8 * (r >> 2) + 4 * hi;
          if (kvb + kvo > qg) p[r] = -1e30f;
          if (kvb + 32 + kvo > qg) p[16 + r] = -1e30f;
        }
      }
      float mx = p[0];
#pragma unroll
      for (int r = 1; r < 32; ++r) mx = fmaxf(mx, p[r]);
      mx = fmaxf(mx, __shfl_xor(mx, 32));
      if (!__all(mx <= m_run + 8.0f)) {  // defer-max: P bounded by 2^8
        const float mn = fmaxf(m_run, mx);
        const float al = __builtin_amdgcn_exp2f(m_run - mn);
        m_run = mn;
        l_run *= al;
        lred[wid * 32 + ln31] = al;
        asm volatile("s_waitcnt lgkmcnt(0)" ::: "memory");
        __builtin_amdgcn_sched_barrier(0);
#pragma unroll
        for (int r = 0; r < 16; ++r) {
          const float a = lred[wid * 32 + (r & 3) + 8 * (r >> 2) + 4 * hi];
          o0[r] *= a;
          o1[r] *= a;
        }
      }
      float ps = 0.f;
#pragma unroll
      for (int r = 0; r < 32; ++r) {
        p[r] = __builtin_amdgcn_exp2f(p[r] - m_run);
        ps += p[r];
      }
      ps += __shfl_xor(ps, 32);
      l_run += ps;
      unsigned c[16];
#pragma unroll
      for (int i = 0; i < 16; ++i) {
        unsigned rr;
        asm("v_cvt_pk_bf16_f32 %0, %1, %2" : "=v"(rr) : "v"(p[2 * i]), "v"(p[2 * i + 1]));
        c[i] = rr;
      }
      bfv8 paf[4];
#pragma unroll
      for (int fI = 0; fI < 4; ++fI) {
        unsigned a0 = c[fI * 4 + 0], b0 = c[fI * 4 + 2];
        unsigned a1 = c[fI * 4 + 1], b1 = c[fI * 4 + 3];
        swap32(a0, b0, hi);
        swap32(a1, b1, hi);
        union { unsigned u[4]; bfv8 v; } w;
        w.u[0] = a0; w.u[1] = a1; w.u[2] = b0; w.u[3] = b1;
        paf[fI] = w.v;
      }
      __builtin_amdgcn_s_setprio(1);
#pragma unroll
      for (int ss = 0; ss < 4; ++ss) {
        const int byt = ss * 32 + hi * 16;
        const bfv8 v0 = *(const bfv8*)(ldsV + ln31 * 128 + (byt ^ swz));
        const bfv8 v1 = *(const bfv8*)(ldsV + (32 + ln31) * 128 + (byt ^ swz));
        o0 = mfma32(paf[ss], v0, o0);
        o1 = mfma32(paf[ss], v1, o1);
      }
      __builtin_amdgcn_s_setprio(0);
    }
    if (st) {
      asm volatile("s_waitcnt vmcnt(4)" ::: "memory");
    } else if (t + 1 < nt) {
      asm volatile("s_waitcnt vmcnt(0)" ::: "memory");
    }
    asm volatile("" ::: "memory");
    __builtin_amdgcn_s_barrier();
  }
#undef ATTN_STAGE

  lred[wid * 32 + ln31] = l_run;
  asm volatile("s_waitcnt lgkmcnt(0)" ::: "memory");
  __builtin_amdgcn_sched_barrier(0);
  const int nidx = head >> 5, hh = head & 31;
#pragma unroll
  for (int r = 0; r < 16; ++r) {
    const int qrow = qw + (r & 3) + 8 * (r >> 2) + 4 * hi;
    const float inv = 1.0f / lred[wid * 32 + (r & 3) + 8 * (r >> 2) + 4 * hi];
    __hip_bfloat16* dst = ob + ((size_t)nidx * SEQ + qrow) * DIMM + hh * 64;
    dst[ln31] = __float2bfloat16(o0[r] * inv);
    dst[32 + ln31] = __float2bfloat16(o1[r] * inv);
  }
}

extern "C" void kernel_launch(void* const* d_in, const int* in_sizes, int n_in,
                              void* d_out, int out_size, void* d_ws, size_t ws_size,
                              hipStream_t stream) {
  const float* x = (const float*)d_in[0];
  const float* ln_w = (const float*)d_in[1];
  const float* ln_b = (const float*)d_in[2];
  const float* w_qkv = (const float*)d_in[3];
  const float* b_qkv = (const float*)d_in[4];
  const float* w_out = (const float*)d_in[5];
  const float* b_out = (const float*)d_in[6];
  float* out = (float*)d_out;

  char* ws = (char*)d_ws;
  size_t off = 0;
  auto alloc = [&](size_t bytes) -> char* {
    char* p = ws + off;
    off += (bytes + 255) & ~(size_t)255;
    return p;
  };
  __hip_bfloat16* h = (__hip_bfloat16*)alloc((size_t)ROWS * DIMM * 2);
  __hip_bfloat16* wqkvT = (__hip_bfloat16*)alloc((size_t)3 * DIMM * DIMM * 2);
  __hip_bfloat16* woutT = (__hip_bfloat16*)alloc((size_t)DIMM * DIMM * 2);
  __hip_bfloat16* qbuf = (__hip_bfloat16*)alloc((size_t)ROWS * DIMM * 2);
  __hip_bfloat16* kbuf = (__hip_bfloat16*)alloc((size_t)ROWS * DIMM * 2);
  __hip_bfloat16* vtbuf = (__hip_bfloat16*)alloc((size_t)ROWS * DIMM * 2);
  __hip_bfloat16* obuf = (__hip_bfloat16*)alloc((size_t)ROWS * DIMM * 2);
  float* ct = (float*)alloc((size_t)SEQ * NFREQ * 4);
  float* st = (float*)alloc((size_t)SEQ * NFREQ * 4);

  prep_kernel<<<dim3(PB_TOTAL), dim3(256), 0, stream>>>(
      x, ln_w, ln_b, h, w_qkv, wqkvT, w_out, woutT, ct, st);
  gemm_qkv_kernel<<<dim3(3 * DIMM / 128, ROWS / 256), dim3(512), 0, stream>>>(
      h, wqkvT, b_qkv, ct, st, qbuf, kbuf, vtbuf);
  attn_kernel<<<dim3(NBATCH * NHEADS, SEQ / 128), dim3(256), 0, stream>>>(
      qbuf, kbuf, vtbuf, obuf);
  gemm_out_kernel<<<dim3(DIMM / 128, ROWS / 256), dim3(512), 0, stream>>>(
      obuf, woutT, b_out, x, out);
}

// Round 15
// 243.637 us; speedup vs baseline: 1.2078x; 1.0432x over previous
//
#include <hip/hip_runtime.h>
#include <hip/hip_bf16.h>
#include <cstdint>
#include <cstddef>

#define DIMM 2048
#define NHEADS 32
#define HDIM 64
#define SEQ 2048
#define NBATCH 2
#define ROWS 4096
#define NFREQ 16
#define NKT3 32  // K=2048 / BK=64
#define QSCALE 0.1803368802f  // 0.125 * log2(e): folded into q -> softmax in exp2 domain

// prep_kernel block ranges
#define PB_LN ROWS                           // 4096
#define PB_TQKV (192 * 64)                   // 12288
#define PB_TOUT (64 * 64)                    // 4096
#define PB_ROPE ((SEQ * NFREQ + 255) / 256)  // 128
#define PB_TOTAL (PB_LN + PB_TQKV + PB_TOUT + PB_ROPE)

typedef __bf16 bfv8 __attribute__((ext_vector_type(8)));
typedef float f32x4v __attribute__((ext_vector_type(4)));
typedef float f32x16 __attribute__((ext_vector_type(16)));

__device__ __forceinline__ void gload16(const void* g, void* l) {
  __builtin_amdgcn_global_load_lds((const __attribute__((address_space(1))) void*)g,
                                   (__attribute__((address_space(3))) void*)l, 16, 0, 0);
}

__device__ __forceinline__ f32x4v mfma16(bfv8 a, bfv8 b, f32x4v c) {
  return __builtin_amdgcn_mfma_f32_16x16x32_bf16(a, b, c, 0, 0, 0);
}

__device__ __forceinline__ f32x16 mfma32(bfv8 a, bfv8 b, f32x16 c) {
  return __builtin_amdgcn_mfma_f32_32x32x16_bf16(a, b, c, 0, 0, 0);
}

__device__ __forceinline__ unsigned short f2bfu(float f) {
  __hip_bfloat16 h = __float2bfloat16(f);
  return __builtin_bit_cast(unsigned short, h);
}

__device__ __forceinline__ void swap32(unsigned& a, unsigned& b, const int hi) {
  const unsigned ta = (unsigned)__shfl_xor((int)a, 32);
  const unsigned tb = (unsigned)__shfl_xor((int)b, 32);
  const unsigned na = hi ? tb : a;
  const unsigned nb = hi ? b : ta;
  a = na;
  b = nb;
}

__device__ __forceinline__ void xcd_swizzle(int& bx, int& by) {
  const int gx = gridDim.x, nwg = gx * gridDim.y;
  const int orig = blockIdx.y * gx + blockIdx.x;
  const int q = nwg >> 3, r = nwg & 7;
  const int xcd = orig & 7, loc = orig >> 3;
  const int wg = (xcd < r ? xcd * (q + 1) : r * (q + 1) + (xcd - r) * q) + loc;
  bx = wg % gx;
  by = wg / gx;
}

// ---------------- fused prep: LN | transpose(w_qkv) | transpose(w_out) | rope ----------
__device__ __forceinline__ void transpose32_body(const float* __restrict__ W,
                                                 __hip_bfloat16* __restrict__ WT,
                                                 int K, int N, int n0, int k0,
                                                 float* tile /*[32][33]*/) {
  const int tid = threadIdx.x;
  const int tx = tid & 31, ty = tid >> 5;
#pragma unroll
  for (int j = 0; j < 4; ++j)
    tile[(ty + j * 8) * 33 + tx] = W[(size_t)(k0 + ty + j * 8) * N + n0 + tx];
  __syncthreads();
#pragma unroll
  for (int j = 0; j < 4; ++j)
    WT[(size_t)(n0 + ty + j * 8) * K + k0 + tx] = __float2bfloat16(tile[tx * 33 + ty + j * 8]);
}

__global__ __launch_bounds__(256) void prep_kernel(
    const float* __restrict__ x, const float* __restrict__ lw, const float* __restrict__ lb,
    __hip_bfloat16* __restrict__ h, const float* __restrict__ w_qkv,
    __hip_bfloat16* __restrict__ wqkvT, const float* __restrict__ w_out,
    __hip_bfloat16* __restrict__ woutT, float* __restrict__ ct, float* __restrict__ st) {
  __shared__ float pls[32 * 33];
  const int b = blockIdx.x;
  const int t = threadIdx.x;
  if (b < PB_LN) {
    const int row = b;
    const float4* xr = (const float4*)(x + (size_t)row * DIMM);
    float4 a = xr[t * 2], bb4 = xr[t * 2 + 1];
    float e[8];
    *(float4*)e = a; *(float4*)(e + 4) = bb4;
    float s = 0.f, ss = 0.f;
#pragma unroll
    for (int j = 0; j < 8; ++j) { s += e[j]; ss += e[j] * e[j]; }
#pragma unroll
    for (int o = 1; o < 64; o <<= 1) { s += __shfl_xor(s, o); ss += __shfl_xor(ss, o); }
    float* red = pls;
    const int wid = t >> 6;
    if ((t & 63) == 0) { red[wid * 2] = s; red[wid * 2 + 1] = ss; }
    __syncthreads();
    s = red[0] + red[2] + red[4] + red[6];
    ss = red[1] + red[3] + red[5] + red[7];
    const float mu = s * (1.f / DIMM);
    const float var = ss * (1.f / DIMM) - mu * mu;
    const float rs = rsqrtf(var + 1e-5f);
    const float4* w4 = (const float4*)lw;
    const float4* b4 = (const float4*)lb;
    float4 wa = w4[t * 2], wb = w4[t * 2 + 1], ba = b4[t * 2], bb = b4[t * 2 + 1];
    float wv[8], bv[8];
    *(float4*)wv = wa; *(float4*)(wv + 4) = wb;
    *(float4*)bv = ba; *(float4*)(bv + 4) = bb;
    unsigned short hv[8];
#pragma unroll
    for (int j = 0; j < 8; ++j)
      hv[j] = f2bfu((e[j] - mu) * rs * wv[j] + bv[j]);
    *(uint4*)((char*)h + (size_t)row * (DIMM * 2) + t * 16) = *(uint4*)hv;
  } else if (b < PB_LN + PB_TQKV) {
    const int i = b - PB_LN;
    const int n0 = (i % 192) * 32, k0 = (i / 192) * 32;
    transpose32_body(w_qkv, wqkvT, DIMM, 3 * DIMM, n0, k0, pls);
  } else if (b < PB_LN + PB_TQKV + PB_TOUT) {
    const int i = b - PB_LN - PB_TQKV;
    const int n0 = (i % 64) * 32, k0 = (i / 64) * 32;
    transpose32_body(w_out, woutT, DIMM, DIMM, n0, k0, pls);
  } else {
    const int i = (b - PB_LN - PB_TQKV - PB_TOUT) * 256 + t;
    if (i < SEQ * NFREQ) {
      const int pos = i >> 4, f = i & 15;
      const float freq = powf(10000.0f, -(float)f / 16.0f);
      const float ang = (float)pos * freq;
      ct[i] = cosf(ang);
      st[i] = sinf(ang);
    }
  }
}

// ======== 256x128xK GEMM, BK=64, 8 waves = 2M x 2N x 2K, ring-3 LDS (R7, proven) ========
__device__ __forceinline__ void stageA64(const char* Ab, int brow, int kt,
                                         char* bufA, int c, int lane) {
  const int row = c * 8 + (lane >> 3);
  const int src = ((lane & 7) * 16) ^ ((row & 7) << 4);
  gload16(Ab + (size_t)(brow + row) * 4096 + kt * 128 + src, bufA + c * 1024);
}
__device__ __forceinline__ void stageB64(const char* Bb, int bcol, int kt,
                                         char* bufB, int c, int lane) {
  const int row = c * 8 + (lane >> 3);
  const int src = ((lane & 7) * 16) ^ ((row & 7) << 4);
  gload16(Bb + (size_t)(bcol + row) * 4096 + kt * 128 + src, bufB + c * 1024);
}

__device__ __forceinline__ void gemm_core3(const char* Ab, const char* Bb,
                                           int brow, int bcol, char* lds,
                                           f32x4v acc[8][4]) {
  const int tid = threadIdx.x, lane = tid & 63, wid = tid >> 6;
  const int g = lane >> 4, ln15 = lane & 15;
  const int wr = wid >> 2, wc = (wid >> 1) & 1, wk = wid & 1;
  const int kb = wk * 64;
#pragma unroll
  for (int t = 0; t < 2; ++t) {
    char* bufA = lds + t * 49152;
    char* bufB = bufA + 32768;
    stageA64(Ab, brow, t, bufA, wid, lane);
    stageA64(Ab, brow, t, bufA, wid + 8, lane);
    stageA64(Ab, brow, t, bufA, wid + 16, lane);
    stageA64(Ab, brow, t, bufA, wid + 24, lane);
    stageB64(Bb, bcol, t, bufB, wid, lane);
    stageB64(Bb, bcol, t, bufB, wid + 8, lane);
  }
  asm volatile("s_waitcnt vmcnt(6)" ::: "memory");
  __builtin_amdgcn_s_barrier();

  for (int t = 0; t < NKT3; ++t) {
    char* bufA = lds + (t % 3) * 49152;
    char* bufB = bufA + 32768;
    char* nbufA = lds + ((t + 2) % 3) * 49152;
    char* nbufB = nbufA + 32768;
    const bool st = (t + 2 < NKT3);
    bfv8 af[4], bfr[4];
#pragma unroll
    for (int mi = 0; mi < 4; ++mi) {
      const int ra = wr * 128 + mi * 16 + ln15;
      af[mi] = *(const bfv8*)(bufA + (size_t)ra * 128 + ((kb + g * 16) ^ ((ra & 7) << 4)));
    }
#pragma unroll
    for (int nf = 0; nf < 4; ++nf) {
      const int rb = wc * 64 + nf * 16 + ln15;
      bfr[nf] = *(const bfv8*)(bufB + (size_t)rb * 128 + ((kb + g * 16) ^ ((rb & 7) << 4)));
    }
    if (st) {
      stageA64(Ab, brow, t + 2, nbufA, wid, lane);
      stageA64(Ab, brow, t + 2, nbufA, wid + 8, lane);
      stageB64(Bb, bcol, t + 2, nbufB, wid, lane);
    }
    __builtin_amdgcn_s_setprio(1);
#pragma unroll
    for (int mi = 0; mi < 4; ++mi)
#pragma unroll
      for (int nf = 0; nf < 4; ++nf)
        acc[mi][nf] = mfma16(af[mi], bfr[nf], acc[mi][nf]);
    __builtin_amdgcn_s_setprio(0);
    bfv8 ao[4];
#pragma unroll
    for (int mi = 0; mi < 4; ++mi) {
      const int ra = wr * 128 + (4 + mi) * 16 + ln15;
      ao[mi] = *(const bfv8*)(bufA + (size_t)ra * 128 + ((kb + g * 16) ^ ((ra & 7) << 4)));
    }
    if (st) {
      stageA64(Ab, brow, t + 2, nbufA, wid + 16, lane);
      stageA64(Ab, brow, t + 2, nbufA, wid + 24, lane);
      stageB64(Bb, bcol, t + 2, nbufB, wid + 8, lane);
    }
    __builtin_amdgcn_s_setprio(1);
#pragma unroll
    for (int mi = 0; mi < 4; ++mi)
#pragma unroll
      for (int nf = 0; nf < 4; ++nf)
        acc[4 + mi][nf] = mfma16(ao[mi], bfr[nf], acc[4 + mi][nf]);
    __builtin_amdgcn_s_setprio(0);
    if (st) {
      asm volatile("s_waitcnt vmcnt(6)" ::: "memory");
    } else if (t == NKT3 - 2) {
      asm volatile("s_waitcnt vmcnt(0)" ::: "memory");
    }
    asm volatile("" ::: "memory");
    __builtin_amdgcn_s_barrier();
  }
}

__device__ __forceinline__ void kreduce(char* lds, f32x4v acc[8][4], f32x4v ak[4][4],
                                        int wid, int lane, int wk) {
  char* reg = lds + (size_t)wid * 16384;
#pragma unroll
  for (int q = 0; q < 4; ++q)
#pragma unroll
    for (int nf = 0; nf < 4; ++nf)
      *(f32x4v*)(reg + (q * 4 + nf) * 1024 + lane * 16) = acc[wk ? q : 4 + q][nf];
  __syncthreads();
  const char* preg = lds + (size_t)(wid ^ 1) * 16384;
#pragma unroll
  for (int q = 0; q < 4; ++q)
#pragma unroll
    for (int nf = 0; nf < 4; ++nf)
      ak[q][nf] = acc[wk ? 4 + q : q][nf] +
                  *(const f32x4v*)(preg + (q * 4 + nf) * 1024 + lane * 16);
  __syncthreads();
}

// ---------------- QKV GEMM + bias + RoPE (q pre-scaled by QSCALE); v -> VT ----------------
__global__ __launch_bounds__(512, 2) void gemm_qkv_kernel(
    const __hip_bfloat16* __restrict__ A, const __hip_bfloat16* __restrict__ BT,
    const float* __restrict__ bqkv, const float* __restrict__ ct, const float* __restrict__ st,
    __hip_bfloat16* __restrict__ qb, __hip_bfloat16* __restrict__ kb,
    __hip_bfloat16* __restrict__ vb) {
  __shared__ char lds[147456];
  const f32x4v fz = {0.f, 0.f, 0.f, 0.f};
  f32x4v acc[8][4];
#pragma unroll
  for (int mf = 0; mf < 8; ++mf)
#pragma unroll
    for (int nf = 0; nf < 4; ++nf) acc[mf][nf] = fz;
  int bx, by;
  xcd_swizzle(bx, by);
  const int brow = by * 256, bcol = bx * 128;
  gemm_core3((const char*)A, (const char*)BT, brow, bcol, lds, acc);

  const int tid = threadIdx.x, lane = tid & 63, wid = tid >> 6;
  const int g = lane >> 4, ln15 = lane & 15;
  const int wr = wid >> 2, wc = (wid >> 1) & 1, wk = wid & 1;
  f32x4v ak[4][4];
  kreduce(lds, acc, ak, wid, lane, wk);

  const int cb = bcol + wc * 64;
  const int which = cb >> 11;
  const int head = (cb & 2047) >> 6;
  const int rowbase = brow + wr * 128 + wk * 64;
  const int nidx = rowbase >> 11;
  const int posb = rowbase & 2047;
  float bias[4];
#pragma unroll
  for (int nf = 0; nf < 4; ++nf) bias[nf] = bqkv[cb + nf * 16 + ln15];

  if (which == 2) {
    char* tp = lds + wid * 8192;
    const size_t vhead = ((size_t)nidx * NHEADS + head) * (HDIM * SEQ);
#pragma unroll
    for (int q = 0; q < 4; ++q)
#pragma unroll
      for (int r = 0; r < 4; ++r) {
        const int posl = q * 16 + g * 4 + r;
#pragma unroll
        for (int nf = 0; nf < 4; ++nf) {
          const int d = nf * 16 + ln15;
          *(unsigned short*)(tp + d * 128 + ((posl * 2) ^ ((d & 7) << 4))) =
              f2bfu(ak[q][nf][r] + bias[nf]);
        }
      }
    asm volatile("s_waitcnt lgkmcnt(0)" ::: "memory");
    __builtin_amdgcn_sched_barrier(0);
#pragma unroll
    for (int i = 0; i < 8; ++i) {
      const int dl = i * 8 + (lane >> 3);
      const int cs = (lane & 7) ^ (dl & 7);
      const uint4 val = *(const uint4*)(tp + dl * 128 + cs * 16);
      *(uint4*)((char*)vb + (vhead + (size_t)dl * SEQ + posb + (lane & 7) * 8) * 2) = val;
    }
  } else {
    __hip_bfloat16* dst = (which == 0) ? qb : kb;
    const float qs = (which == 0) ? QSCALE : 1.0f;
    char* tp = lds + wid * 8192;
#pragma unroll
    for (int q = 0; q < 4; ++q)
#pragma unroll
      for (int r = 0; r < 4; ++r) {
        const int posl = q * 16 + g * 4 + r;
        const int pos = posb + posl;
        float v0 = ak[q][0][r] + bias[0];
        float v1 = ak[q][1][r] + bias[1];
        float v2 = ak[q][2][r] + bias[2];
        float v3 = ak[q][3][r] + bias[3];
        const float c0 = ct[pos * 16 + ln15], s0 = st[pos * 16 + ln15];
        const float x1 = v0, x2 = v1;
        v0 = (x1 * c0 - x2 * s0) * qs;
        v1 = (x2 * c0 + x1 * s0) * qs;
        v2 *= qs;
        v3 *= qs;
        const int sw2 = (posl & 7) << 4;
        char* rowp = tp + posl * 128;
        *(unsigned short*)(rowp + ((ln15 * 2) ^ sw2)) = f2bfu(v0);
        *(unsigned short*)(rowp + ((32 + ln15 * 2) ^ sw2)) = f2bfu(v1);
        *(unsigned short*)(rowp + ((64 + ln15 * 2) ^ sw2)) = f2bfu(v2);
        *(unsigned short*)(rowp + ((96 + ln15 * 2) ^ sw2)) = f2bfu(v3);
      }
    asm volatile("s_waitcnt lgkmcnt(0)" ::: "memory");
    __builtin_amdgcn_sched_barrier(0);
    const size_t qkbase = (((size_t)(nidx * NHEADS + head)) * SEQ + posb) * HDIM;
#pragma unroll
    for (int i = 0; i < 8; ++i) {
      const int rr = i * 8 + (lane >> 3);
      const int cs = (lane & 7) ^ (rr & 7);
      const uint4 val = *(const uint4*)(tp + rr * 128 + cs * 16);
      *(uint4*)((char*)dst + (qkbase + (size_t)rr * HDIM) * 2 + (lane & 7) * 16) = val;
    }
  }
}

// ---------------- out-proj GEMM + bias + residual -> f32 out (LDS-repacked) ----------
__global__ __launch_bounds__(512, 2) void gemm_out_kernel(
    const __hip_bfloat16* __restrict__ A, const __hip_bfloat16* __restrict__ BT,
    const float* __restrict__ bout, const float* __restrict__ skip,
    float* __restrict__ out) {
  __shared__ char lds[147456];
  const f32x4v fz = {0.f, 0.f, 0.f, 0.f};
  f32x4v acc[8][4];
#pragma unroll
  for (int mf = 0; mf < 8; ++mf)
#pragma unroll
    for (int nf = 0; nf < 4; ++nf) acc[mf][nf] = fz;
  int bx, by;
  xcd_swizzle(bx, by);
  const int brow = by * 256, bcol = bx * 128;
  gemm_core3((const char*)A, (const char*)BT, brow, bcol, lds, acc);

  const int tid = threadIdx.x, lane = tid & 63, wid = tid >> 6;
  const int g = lane >> 4, ln15 = lane & 15;
  const int wr = wid >> 2, wc = (wid >> 1) & 1, wk = wid & 1;
  f32x4v ak[4][4];
  kreduce(lds, acc, ak, wid, lane, wk);

  const int rowbase = brow + wr * 128 + wk * 64;
  char* tp = lds + wid * 16384;
#pragma unroll
  for (int q = 0; q < 4; ++q)
#pragma unroll
    for (int r = 0; r < 4; ++r) {
      const int posl = q * 16 + g * 4 + r;
      const int sw2 = ((posl >> 2) & 3) << 6;
      char* rowp = tp + posl * 256;
#pragma unroll
      for (int nf = 0; nf < 4; ++nf)
        *(float*)(rowp + ((nf * 64 + ln15 * 4) ^ sw2)) = ak[q][nf][r];
    }
  asm volatile("s_waitcnt lgkmcnt(0)" ::: "memory");
  __builtin_amdgcn_sched_barrier(0);
  const int colb = bcol + wc * 64;
#pragma unroll
  for (int i = 0; i < 16; ++i) {
    const int rr = i * 4 + (lane >> 4);
    const int cp = lane & 15;
    const float4 a4 = *(const float4*)(tp + rr * 256 + cp * 16);
    const int lc = (cp * 16) ^ (((rr >> 2) & 3) << 6);
    const int col = colb + (lc >> 2);
    const int row = rowbase + rr;
    const float4 sk = *(const float4*)(skip + (size_t)row * DIMM + col);
    const float4 bo = *(const float4*)(bout + col);
    float4 o4;
    o4.x = a4.x + sk.x + bo.x;
    o4.y = a4.y + sk.y + bo.y;
    o4.z = a4.z + sk.z + bo.z;
    o4.w = a4.w + sk.w + bo.w;
    *(float4*)(out + (size_t)row * DIMM + col) = o4;
  }
}

// ---- causal flash attention: 8-wave blocks (256 q-rows), ring-3 KV, exp2 softmax ----
// Per-wave code identical to R14; geometry: 512 threads, q0=qbi*256, nt=4*qbi+4,
// staging 2 gloads/thread/tile (512 threads cover 8KB K + 8KB V), vmcnt 4->2.
__global__ __launch_bounds__(512) void attn_kernel(
    const __hip_bfloat16* __restrict__ qb, const __hip_bfloat16* __restrict__ kb,
    const __hip_bfloat16* __restrict__ vtb, __hip_bfloat16* __restrict__ ob) {
  __shared__ char sm[50176];  // K ring 3x8K | VT ring 3x8K | lred 1K
  float* lred = (float*)(sm + 49152);
  const int tid = threadIdx.x, lane = tid & 63, wid = tid >> 6;
  const int ln31 = lane & 31, hi = lane >> 5;
  const int head = blockIdx.x;
  const int qbi = (int)gridDim.y - 1 - (int)blockIdx.y;  // heavy blocks dispatch first
  const size_t hb = (size_t)head * (SEQ * HDIM);
  const int q0 = qbi * 256;
  const int qw = q0 + wid * 32;
  const int qg = qw + ln31;
  const int nt = qbi * 4 + 4;
  const char* Kg = (const char*)(kb + hb);
  const char* Vg = (const char*)(vtb + hb);

  bfv8 qf[4];
  {
    const char* Qp = (const char*)(qb + hb) + (size_t)(qw + ln31) * 128 + hi * 16;
#pragma unroll
    for (int j = 0; j < 4; ++j) qf[j] = *(const bfv8*)(Qp + j * 32);
  }

  f32x16 o0, o1;
#pragma unroll
  for (int i = 0; i < 16; ++i) { o0[i] = 0.f; o1[i] = 0.f; }
  float m_run = -1e30f, l_run = 0.f;
  const int swz = (ln31 & 7) << 4;

#define ATTN_STAGE(T, B)                                                            \
  {                                                                                 \
    const int kvs = (T)*64;                                                         \
    const int f = tid * 16;                                                         \
    const int row = f >> 7;                                                         \
    const int src = (f & 127) ^ ((row & 7) << 4);                                   \
    gload16(Kg + (size_t)(kvs + row) * 128 + src, sm + (B)*8192 + f);               \
    gload16(Vg + (size_t)row * 4096 + (size_t)kvs * 2 + src,                        \
            sm + 24576 + (B)*8192 + f);                                             \
  }

  ATTN_STAGE(0, 0);
  ATTN_STAGE(1, 1);
  asm volatile("s_waitcnt vmcnt(2)" ::: "memory");  // tile 0 landed; tile 1 in flight
  __builtin_amdgcn_s_barrier();

  for (int t = 0; t < nt; ++t) {
    const int kvb = t * 64;
    const bool st = (t + 2 < nt);
    if (st) ATTN_STAGE(t + 2, (t + 2) % 3);
    if (kvb <= qw + 31) {
      const char* ldsK = sm + (t % 3) * 8192;
      const char* ldsV = sm + 24576 + (t % 3) * 8192;
      f32x16 s0, s1;
#pragma unroll
      for (int i = 0; i < 16; ++i) { s0[i] = 0.f; s1[i] = 0.f; }
      __builtin_amdgcn_s_setprio(1);
#pragma unroll
      for (int j = 0; j < 4; ++j) {
        const int byt = j * 32 + hi * 16;
        const bfv8 k0 = *(const bfv8*)(ldsK + ln31 * 128 + (byt ^ swz));
        const bfv8 k1 = *(const bfv8*)(ldsK + (32 + ln31) * 128 + (byt ^ swz));
        s0 = mfma32(k0, qf[j], s0);
        s1 = mfma32(k1, qf[j], s1);
      }
      __builtin_amdgcn_s_setprio(0);
      float p[32];
#pragma unroll
      for (int r = 0; r < 16; ++r) { p[r] = s0[r]; p[16 + r] = s1[r]; }
      if (kvb + 63 > qw) {  // diagonal tile for this wave (compare vs MIN q-row)
#pragma unroll
        for (int r = 0; r < 16; ++r) {
          const int kvo = (r & 3) + 8 * (r >> 2) + 4 * hi;
          if (kvb + kvo > qg) p[r] = -1e30f;
          if (kvb + 32 + kvo > qg) p[16 + r] = -1e30f;
        }
      }
      float mx = p[0];
#pragma unroll
      for (int r = 1; r < 32; ++r) mx = fmaxf(mx, p[r]);
      mx = fmaxf(mx, __shfl_xor(mx, 32));
      if (!__all(mx <= m_run + 8.0f)) {  // defer-max: P bounded by 2^8
        const float mn = fmaxf(m_run, mx);
        const float al = __builtin_amdgcn_exp2f(m_run - mn);
        m_run = mn;
        l_run *= al;
        lred[wid * 32 + ln31] = al;
        asm volatile("s_waitcnt lgkmcnt(0)" ::: "memory");
        __builtin_amdgcn_sched_barrier(0);
#pragma unroll
        for (int r = 0; r < 16; ++r) {
          const float a = lred[wid * 32 + (r & 3) + 8 * (r >> 2) + 4 * hi];
          o0[r] *= a;
          o1[r] *= a;
        }
      }
      float ps = 0.f;
#pragma unroll
      for (int r = 0; r < 32; ++r) {
        p[r] = __builtin_amdgcn_exp2f(p[r] - m_run);
        ps += p[r];
      }
      ps += __shfl_xor(ps, 32);
      l_run += ps;
      unsigned c[16];
#pragma unroll
      for (int i = 0; i < 16; ++i) {
        unsigned rr;
        asm("v_cvt_pk_bf16_f32 %0, %1, %2" : "=v"(rr) : "v"(p[2 * i]), "v"(p[2 * i + 1]));
        c[i] = rr;
      }
      bfv8 paf[4];
#pragma unroll
      for (int fI = 0; fI < 4; ++fI) {
        unsigned a0 = c[fI * 4 + 0], b0 = c[fI * 4 + 2];
        unsigned a1 = c[fI * 4 + 1], b1 = c[fI * 4 + 3];
        swap32(a0, b0, hi);
        swap32(a1, b1, hi);
        union { unsigned u[4]; bfv8 v; } w;
        w.u[0] = a0; w.u[1] = a1; w.u[2] = b0; w.u[3] = b1;
        paf[fI] = w.v;
      }
      __builtin_amdgcn_s_setprio(1);
#pragma unroll
      for (int ss = 0; ss < 4; ++ss) {
        const int byt = ss * 32 + hi * 16;
        const bfv8 v0 = *(const bfv8*)(ldsV + ln31 * 128 + (byt ^ swz));
        const bfv8 v1 = *(const bfv8*)(ldsV + (32 + ln31) * 128 + (byt ^ swz));
        o0 = mfma32(paf[ss], v0, o0);
        o1 = mfma32(paf[ss], v1, o1);
      }
      __builtin_amdgcn_s_setprio(0);
    }
    if (st) {
      asm volatile("s_waitcnt vmcnt(2)" ::: "memory");  // t+1 landed; t+2 in flight
    } else if (t + 1 < nt) {
      asm volatile("s_waitcnt vmcnt(0)" ::: "memory");  // drain final tile
    }
    asm volatile("" ::: "memory");
    __builtin_amdgcn_s_barrier();
  }
#undef ATTN_STAGE

  lred[wid * 32 + ln31] = l_run;
  asm volatile("s_waitcnt lgkmcnt(0)" ::: "memory");
  __builtin_amdgcn_sched_barrier(0);
  const int nidx = head >> 5, hh = head & 31;
#pragma unroll
  for (int r = 0; r < 16; ++r) {
    const int qrow = qw + (r & 3) + 8 * (r >> 2) + 4 * hi;
    const float inv = 1.0f / lred[wid * 32 + (r & 3) + 8 * (r >> 2) + 4 * hi];
    __hip_bfloat16* dst = ob + ((size_t)nidx * SEQ + qrow) * DIMM + hh * 64;
    dst[ln31] = __float2bfloat16(o0[r] * inv);
    dst[32 + ln31] = __float2bfloat16(o1[r] * inv);
  }
}

extern "C" void kernel_launch(void* const* d_in, const int* in_sizes, int n_in,
                              void* d_out, int out_size, void* d_ws, size_t ws_size,
                              hipStream_t stream) {
  const float* x = (const float*)d_in[0];
  const float* ln_w = (const float*)d_in[1];
  const float* ln_b = (const float*)d_in[2];
  const float* w_qkv = (const float*)d_in[3];
  const float* b_qkv = (const float*)d_in[4];
  const float* w_out = (const float*)d_in[5];
  const float* b_out = (const float*)d_in[6];
  float* out = (float*)d_out;

  char* ws = (char*)d_ws;
  size_t off = 0;
  auto alloc = [&](size_t bytes) -> char* {
    char* p = ws + off;
    off += (bytes + 255) & ~(size_t)255;
    return p;
  };
  __hip_bfloat16* h = (__hip_bfloat16*)alloc((size_t)ROWS * DIMM * 2);
  __hip_bfloat16* wqkvT = (__hip_bfloat16*)alloc((size_t)3 * DIMM * DIMM * 2);
  __hip_bfloat16* woutT = (__hip_bfloat16*)alloc((size_t)DIMM * DIMM * 2);
  __hip_bfloat16* qbuf = (__hip_bfloat16*)alloc((size_t)ROWS * DIMM * 2);
  __hip_bfloat16* kbuf = (__hip_bfloat16*)alloc((size_t)ROWS * DIMM * 2);
  __hip_bfloat16* vtbuf = (__hip_bfloat16*)alloc((size_t)ROWS * DIMM * 2);
  __hip_bfloat16* obuf = (__hip_bfloat16*)alloc((size_t)ROWS * DIMM * 2);
  float* ct = (float*)alloc((size_t)SEQ * NFREQ * 4);
  float* st = (float*)alloc((size_t)SEQ * NFREQ * 4);

  prep_kernel<<<dim3(PB_TOTAL), dim3(256), 0, stream>>>(
      x, ln_w, ln_b, h, w_qkv, wqkvT, w_out, woutT, ct, st);
  gemm_qkv_kernel<<<dim3(3 * DIMM / 128, ROWS / 256), dim3(512), 0, stream>>>(
      h, wqkvT, b_qkv, ct, st, qbuf, kbuf, vtbuf);
  attn_kernel<<<dim3(NBATCH * NHEADS, SEQ / 256), dim3(512), 0, stream>>>(
      qbuf, kbuf, vtbuf, obuf);
  gemm_out_kernel<<<dim3(DIMM / 128, ROWS / 256), dim3(512), 0, stream>>>(
      obuf, woutT, b_out, x, out);
}

// Round 16
// 242.254 us; speedup vs baseline: 1.2147x; 1.0057x over previous
//
#include <hip/hip_runtime.h>
#include <hip/hip_bf16.h>
#include <cstdint>
#include <cstddef>

#define DIMM 2048
#define NHEADS 32
#define HDIM 64
#define SEQ 2048
#define NBATCH 2
#define ROWS 4096
#define NFREQ 16
#define NKT3 32  // K=2048 / BK=64
#define QSCALE 0.1803368802f  // 0.125 * log2(e): folded into q -> softmax in exp2 domain

// prep_kernel block ranges (64x64 transpose tiles)
#define PB_LN ROWS                           // 4096
#define PB_TQKV (96 * 32)                    // 3072
#define PB_TOUT (32 * 32)                    // 1024
#define PB_ROPE ((SEQ * NFREQ + 255) / 256)  // 128
#define PB_TOTAL (PB_LN + PB_TQKV + PB_TOUT + PB_ROPE)

typedef __bf16 bfv8 __attribute__((ext_vector_type(8)));
typedef float f32x4v __attribute__((ext_vector_type(4)));
typedef float f32x16 __attribute__((ext_vector_type(16)));

__device__ __forceinline__ void gload16(const void* g, void* l) {
  __builtin_amdgcn_global_load_lds((const __attribute__((address_space(1))) void*)g,
                                   (__attribute__((address_space(3))) void*)l, 16, 0, 0);
}

__device__ __forceinline__ f32x4v mfma16(bfv8 a, bfv8 b, f32x4v c) {
  return __builtin_amdgcn_mfma_f32_16x16x32_bf16(a, b, c, 0, 0, 0);
}

__device__ __forceinline__ f32x16 mfma32(bfv8 a, bfv8 b, f32x16 c) {
  return __builtin_amdgcn_mfma_f32_32x32x16_bf16(a, b, c, 0, 0, 0);
}

__device__ __forceinline__ unsigned short f2bfu(float f) {
  __hip_bfloat16 h = __float2bfloat16(f);
  return __builtin_bit_cast(unsigned short, h);
}

__device__ __forceinline__ void swap32(unsigned& a, unsigned& b, const int hi) {
  const unsigned ta = (unsigned)__shfl_xor((int)a, 32);
  const unsigned tb = (unsigned)__shfl_xor((int)b, 32);
  const unsigned na = hi ? tb : a;
  const unsigned nb = hi ? b : ta;
  a = na;
  b = nb;
}

__device__ __forceinline__ void xcd_swizzle(int& bx, int& by) {
  const int gx = gridDim.x, nwg = gx * gridDim.y;
  const int orig = blockIdx.y * gx + blockIdx.x;
  const int q = nwg >> 3, r = nwg & 7;
  const int xcd = orig & 7, loc = orig >> 3;
  const int wg = (xcd < r ? xcd * (q + 1) : r * (q + 1) + (xcd - r) * q) + loc;
  bx = wg % gx;
  by = wg / gx;
}

// ---------------- fused prep: LN | transpose(w_qkv) | transpose(w_out) | rope ----------
// 64x64 f32->bf16 transpose tile: float4 loads, LDS [64][68] f32, 2x uint4 stores
// (fully coalesced 128B per 4 lanes on the WT side).
__device__ __forceinline__ void transpose64_body(const float* __restrict__ W,
                                                 __hip_bfloat16* __restrict__ WT,
                                                 int K, int N, int n0, int k0,
                                                 float* pls /*[64][68]*/) {
  const int t = threadIdx.x;
#pragma unroll
  for (int j = 0; j < 4; ++j) {
    const int r = j * 16 + (t >> 4);
    const int c = (t & 15) * 4;
    const float4 v = *(const float4*)(W + (size_t)(k0 + r) * N + n0 + c);
    *(float4*)(pls + r * 68 + c) = v;
  }
  __syncthreads();
  const int n = t >> 2;
  const int kc = (t & 3) * 16;
  unsigned short hv[16];
#pragma unroll
  for (int i = 0; i < 16; ++i) hv[i] = f2bfu(pls[(kc + i) * 68 + n]);
  char* dst = (char*)WT + ((size_t)(n0 + n) * K + k0 + kc) * 2;
  *(uint4*)dst = *(uint4*)hv;
  *(uint4*)(dst + 16) = *(uint4*)(hv + 8);
}

__global__ __launch_bounds__(256) void prep_kernel(
    const float* __restrict__ x, const float* __restrict__ lw, const float* __restrict__ lb,
    __hip_bfloat16* __restrict__ h, const float* __restrict__ w_qkv,
    __hip_bfloat16* __restrict__ wqkvT, const float* __restrict__ w_out,
    __hip_bfloat16* __restrict__ woutT, float* __restrict__ ct, float* __restrict__ st) {
  __shared__ float pls[64 * 68];
  const int b = blockIdx.x;
  const int t = threadIdx.x;
  if (b < PB_LN) {
    const int row = b;
    const float4* xr = (const float4*)(x + (size_t)row * DIMM);
    float4 a = xr[t * 2], bb4 = xr[t * 2 + 1];
    float e[8];
    *(float4*)e = a; *(float4*)(e + 4) = bb4;
    float s = 0.f, ss = 0.f;
#pragma unroll
    for (int j = 0; j < 8; ++j) { s += e[j]; ss += e[j] * e[j]; }
#pragma unroll
    for (int o = 1; o < 64; o <<= 1) { s += __shfl_xor(s, o); ss += __shfl_xor(ss, o); }
    float* red = pls;
    const int wid = t >> 6;
    if ((t & 63) == 0) { red[wid * 2] = s; red[wid * 2 + 1] = ss; }
    __syncthreads();
    s = red[0] + red[2] + red[4] + red[6];
    ss = red[1] + red[3] + red[5] + red[7];
    const float mu = s * (1.f / DIMM);
    const float var = ss * (1.f / DIMM) - mu * mu;
    const float rs = rsqrtf(var + 1e-5f);
    const float4* w4 = (const float4*)lw;
    const float4* b4 = (const float4*)lb;
    float4 wa = w4[t * 2], wb = w4[t * 2 + 1], ba = b4[t * 2], bb = b4[t * 2 + 1];
    float wv[8], bv[8];
    *(float4*)wv = wa; *(float4*)(wv + 4) = wb;
    *(float4*)bv = ba; *(float4*)(bv + 4) = bb;
    unsigned short hv[8];
#pragma unroll
    for (int j = 0; j < 8; ++j)
      hv[j] = f2bfu((e[j] - mu) * rs * wv[j] + bv[j]);
    *(uint4*)((char*)h + (size_t)row * (DIMM * 2) + t * 16) = *(uint4*)hv;
  } else if (b < PB_LN + PB_TQKV) {
    const int i = b - PB_LN;
    const int n0 = (i % 96) * 64, k0 = (i / 96) * 64;
    transpose64_body(w_qkv, wqkvT, DIMM, 3 * DIMM, n0, k0, pls);
  } else if (b < PB_LN + PB_TQKV + PB_TOUT) {
    const int i = b - PB_LN - PB_TQKV;
    const int n0 = (i % 32) * 64, k0 = (i / 32) * 64;
    transpose64_body(w_out, woutT, DIMM, DIMM, n0, k0, pls);
  } else {
    const int i = (b - PB_LN - PB_TQKV - PB_TOUT) * 256 + t;
    if (i < SEQ * NFREQ) {
      const int pos = i >> 4, f = i & 15;
      const float freq = powf(10000.0f, -(float)f / 16.0f);
      const float ang = (float)pos * freq;
      ct[i] = cosf(ang);
      st[i] = sinf(ang);
    }
  }
}

// ======== 256x128xK GEMM, BK=64, 8 waves = 2M x 2N x 2K, ring-3 LDS (R7, proven) ========
__device__ __forceinline__ void stageA64(const char* Ab, int brow, int kt,
                                         char* bufA, int c, int lane) {
  const int row = c * 8 + (lane >> 3);
  const int src = ((lane & 7) * 16) ^ ((row & 7) << 4);
  gload16(Ab + (size_t)(brow + row) * 4096 + kt * 128 + src, bufA + c * 1024);
}
__device__ __forceinline__ void stageB64(const char* Bb, int bcol, int kt,
                                         char* bufB, int c, int lane) {
  const int row = c * 8 + (lane >> 3);
  const int src = ((lane & 7) * 16) ^ ((row & 7) << 4);
  gload16(Bb + (size_t)(bcol + row) * 4096 + kt * 128 + src, bufB + c * 1024);
}

__device__ __forceinline__ void gemm_core3(const char* Ab, const char* Bb,
                                           int brow, int bcol, char* lds,
                                           f32x4v acc[8][4]) {
  const int tid = threadIdx.x, lane = tid & 63, wid = tid >> 6;
  const int g = lane >> 4, ln15 = lane & 15;
  const int wr = wid >> 2, wc = (wid >> 1) & 1, wk = wid & 1;
  const int kb = wk * 64;
#pragma unroll
  for (int t = 0; t < 2; ++t) {
    char* bufA = lds + t * 49152;
    char* bufB = bufA + 32768;
    stageA64(Ab, brow, t, bufA, wid, lane);
    stageA64(Ab, brow, t, bufA, wid + 8, lane);
    stageA64(Ab, brow, t, bufA, wid + 16, lane);
    stageA64(Ab, brow, t, bufA, wid + 24, lane);
    stageB64(Bb, bcol, t, bufB, wid, lane);
    stageB64(Bb, bcol, t, bufB, wid + 8, lane);
  }
  asm volatile("s_waitcnt vmcnt(6)" ::: "memory");
  __builtin_amdgcn_s_barrier();

  for (int t = 0; t < NKT3; ++t) {
    char* bufA = lds + (t % 3) * 49152;
    char* bufB = bufA + 32768;
    char* nbufA = lds + ((t + 2) % 3) * 49152;
    char* nbufB = nbufA + 32768;
    const bool st = (t + 2 < NKT3);
    bfv8 af[4], bfr[4];
#pragma unroll
    for (int mi = 0; mi < 4; ++mi) {
      const int ra = wr * 128 + mi * 16 + ln15;
      af[mi] = *(const bfv8*)(bufA + (size_t)ra * 128 + ((kb + g * 16) ^ ((ra & 7) << 4)));
    }
#pragma unroll
    for (int nf = 0; nf < 4; ++nf) {
      const int rb = wc * 64 + nf * 16 + ln15;
      bfr[nf] = *(const bfv8*)(bufB + (size_t)rb * 128 + ((kb + g * 16) ^ ((rb & 7) << 4)));
    }
    if (st) {
      stageA64(Ab, brow, t + 2, nbufA, wid, lane);
      stageA64(Ab, brow, t + 2, nbufA, wid + 8, lane);
      stageB64(Bb, bcol, t + 2, nbufB, wid, lane);
    }
    __builtin_amdgcn_s_setprio(1);
#pragma unroll
    for (int mi = 0; mi < 4; ++mi)
#pragma unroll
      for (int nf = 0; nf < 4; ++nf)
        acc[mi][nf] = mfma16(af[mi], bfr[nf], acc[mi][nf]);
    __builtin_amdgcn_s_setprio(0);
    bfv8 ao[4];
#pragma unroll
    for (int mi = 0; mi < 4; ++mi) {
      const int ra = wr * 128 + (4 + mi) * 16 + ln15;
      ao[mi] = *(const bfv8*)(bufA + (size_t)ra * 128 + ((kb + g * 16) ^ ((ra & 7) << 4)));
    }
    if (st) {
      stageA64(Ab, brow, t + 2, nbufA, wid + 16, lane);
      stageA64(Ab, brow, t + 2, nbufA, wid + 24, lane);
      stageB64(Bb, bcol, t + 2, nbufB, wid + 8, lane);
    }
    __builtin_amdgcn_s_setprio(1);
#pragma unroll
    for (int mi = 0; mi < 4; ++mi)
#pragma unroll
      for (int nf = 0; nf < 4; ++nf)
        acc[4 + mi][nf] = mfma16(ao[mi], bfr[nf], acc[4 + mi][nf]);
    __builtin_amdgcn_s_setprio(0);
    if (st) {
      asm volatile("s_waitcnt vmcnt(6)" ::: "memory");
    } else if (t == NKT3 - 2) {
      asm volatile("s_waitcnt vmcnt(0)" ::: "memory");
    }
    asm volatile("" ::: "memory");
    __builtin_amdgcn_s_barrier();
  }
}

__device__ __forceinline__ void kreduce(char* lds, f32x4v acc[8][4], f32x4v ak[4][4],
                                        int wid, int lane, int wk) {
  char* reg = lds + (size_t)wid * 16384;
#pragma unroll
  for (int q = 0; q < 4; ++q)
#pragma unroll
    for (int nf = 0; nf < 4; ++nf)
      *(f32x4v*)(reg + (q * 4 + nf) * 1024 + lane * 16) = acc[wk ? q : 4 + q][nf];
  __syncthreads();
  const char* preg = lds + (size_t)(wid ^ 1) * 16384;
#pragma unroll
  for (int q = 0; q < 4; ++q)
#pragma unroll
    for (int nf = 0; nf < 4; ++nf)
      ak[q][nf] = acc[wk ? 4 + q : q][nf] +
                  *(const f32x4v*)(preg + (q * 4 + nf) * 1024 + lane * 16);
  __syncthreads();
}

// ---------------- QKV GEMM + bias + RoPE (q pre-scaled by QSCALE); v -> VT ----------------
__global__ __launch_bounds__(512, 2) void gemm_qkv_kernel(
    const __hip_bfloat16* __restrict__ A, const __hip_bfloat16* __restrict__ BT,
    const float* __restrict__ bqkv, const float* __restrict__ ct, const float* __restrict__ st,
    __hip_bfloat16* __restrict__ qb, __hip_bfloat16* __restrict__ kb,
    __hip_bfloat16* __restrict__ vb) {
  __shared__ char lds[147456];
  const f32x4v fz = {0.f, 0.f, 0.f, 0.f};
  f32x4v acc[8][4];
#pragma unroll
  for (int mf = 0; mf < 8; ++mf)
#pragma unroll
    for (int nf = 0; nf < 4; ++nf) acc[mf][nf] = fz;
  int bx, by;
  xcd_swizzle(bx, by);
  const int brow = by * 256, bcol = bx * 128;
  gemm_core3((const char*)A, (const char*)BT, brow, bcol, lds, acc);

  const int tid = threadIdx.x, lane = tid & 63, wid = tid >> 6;
  const int g = lane >> 4, ln15 = lane & 15;
  const int wr = wid >> 2, wc = (wid >> 1) & 1, wk = wid & 1;
  f32x4v ak[4][4];
  kreduce(lds, acc, ak, wid, lane, wk);

  const int cb = bcol + wc * 64;
  const int which = cb >> 11;
  const int head = (cb & 2047) >> 6;
  const int rowbase = brow + wr * 128 + wk * 64;
  const int nidx = rowbase >> 11;
  const int posb = rowbase & 2047;
  float bias[4];
#pragma unroll
  for (int nf = 0; nf < 4; ++nf) bias[nf] = bqkv[cb + nf * 16 + ln15];

  if (which == 2) {
    char* tp = lds + wid * 8192;
    const size_t vhead = ((size_t)nidx * NHEADS + head) * (HDIM * SEQ);
#pragma unroll
    for (int q = 0; q < 4; ++q)
#pragma unroll
      for (int r = 0; r < 4; ++r) {
        const int posl = q * 16 + g * 4 + r;
#pragma unroll
        for (int nf = 0; nf < 4; ++nf) {
          const int d = nf * 16 + ln15;
          *(unsigned short*)(tp + d * 128 + ((posl * 2) ^ ((d & 7) << 4))) =
              f2bfu(ak[q][nf][r] + bias[nf]);
        }
      }
    asm volatile("s_waitcnt lgkmcnt(0)" ::: "memory");
    __builtin_amdgcn_sched_barrier(0);
#pragma unroll
    for (int i = 0; i < 8; ++i) {
      const int dl = i * 8 + (lane >> 3);
      const int cs = (lane & 7) ^ (dl & 7);
      const uint4 val = *(const uint4*)(tp + dl * 128 + cs * 16);
      *(uint4*)((char*)vb + (vhead + (size_t)dl * SEQ + posb + (lane & 7) * 8) * 2) = val;
    }
  } else {
    __hip_bfloat16* dst = (which == 0) ? qb : kb;
    const float qs = (which == 0) ? QSCALE : 1.0f;
    char* tp = lds + wid * 8192;
#pragma unroll
    for (int q = 0; q < 4; ++q)
#pragma unroll
      for (int r = 0; r < 4; ++r) {
        const int posl = q * 16 + g * 4 + r;
        const int pos = posb + posl;
        float v0 = ak[q][0][r] + bias[0];
        float v1 = ak[q][1][r] + bias[1];
        float v2 = ak[q][2][r] + bias[2];
        float v3 = ak[q][3][r] + bias[3];
        const float c0 = ct[pos * 16 + ln15], s0 = st[pos * 16 + ln15];
        const float x1 = v0, x2 = v1;
        v0 = (x1 * c0 - x2 * s0) * qs;
        v1 = (x2 * c0 + x1 * s0) * qs;
        v2 *= qs;
        v3 *= qs;
        const int sw2 = (posl & 7) << 4;
        char* rowp = tp + posl * 128;
        *(unsigned short*)(rowp + ((ln15 * 2) ^ sw2)) = f2bfu(v0);
        *(unsigned short*)(rowp + ((32 + ln15 * 2) ^ sw2)) = f2bfu(v1);
        *(unsigned short*)(rowp + ((64 + ln15 * 2) ^ sw2)) = f2bfu(v2);
        *(unsigned short*)(rowp + ((96 + ln15 * 2) ^ sw2)) = f2bfu(v3);
      }
    asm volatile("s_waitcnt lgkmcnt(0)" ::: "memory");
    __builtin_amdgcn_sched_barrier(0);
    const size_t qkbase = (((size_t)(nidx * NHEADS + head)) * SEQ + posb) * HDIM;
#pragma unroll
    for (int i = 0; i < 8; ++i) {
      const int rr = i * 8 + (lane >> 3);
      const int cs = (lane & 7) ^ (rr & 7);
      const uint4 val = *(const uint4*)(tp + rr * 128 + cs * 16);
      *(uint4*)((char*)dst + (qkbase + (size_t)rr * HDIM) * 2 + (lane & 7) * 16) = val;
    }
  }
}

// ---------------- out-proj GEMM + bias + residual -> f32 out (LDS-repacked) ----------
__global__ __launch_bounds__(512, 2) void gemm_out_kernel(
    const __hip_bfloat16* __restrict__ A, const __hip_bfloat16* __restrict__ BT,
    const float* __restrict__ bout, const float* __restrict__ skip,
    float* __restrict__ out) {
  __shared__ char lds[147456];
  const f32x4v fz = {0.f, 0.f, 0.f, 0.f};
  f32x4v acc[8][4];
#pragma unroll
  for (int mf = 0; mf < 8; ++mf)
#pragma unroll
    for (int nf = 0; nf < 4; ++nf) acc[mf][nf] = fz;
  int bx, by;
  xcd_swizzle(bx, by);
  const int brow = by * 256, bcol = bx * 128;
  gemm_core3((const char*)A, (const char*)BT, brow, bcol, lds, acc);

  const int tid = threadIdx.x, lane = tid & 63, wid = tid >> 6;
  const int g = lane >> 4, ln15 = lane & 15;
  const int wr = wid >> 2, wc = (wid >> 1) & 1, wk = wid & 1;
  f32x4v ak[4][4];
  kreduce(lds, acc, ak, wid, lane, wk);

  const int rowbase = brow + wr * 128 + wk * 64;
  char* tp = lds + wid * 16384;
#pragma unroll
  for (int q = 0; q < 4; ++q)
#pragma unroll
    for (int r = 0; r < 4; ++r) {
      const int posl = q * 16 + g * 4 + r;
      const int sw2 = ((posl >> 2) & 3) << 6;
      char* rowp = tp + posl * 256;
#pragma unroll
      for (int nf = 0; nf < 4; ++nf)
        *(float*)(rowp + ((nf * 64 + ln15 * 4) ^ sw2)) = ak[q][nf][r];
    }
  asm volatile("s_waitcnt lgkmcnt(0)" ::: "memory");
  __builtin_amdgcn_sched_barrier(0);
  const int colb = bcol + wc * 64;
#pragma unroll
  for (int i = 0; i < 16; ++i) {
    const int rr = i * 4 + (lane >> 4);
    const int cp = lane & 15;
    const float4 a4 = *(const float4*)(tp + rr * 256 + cp * 16);
    const int lc = (cp * 16) ^ (((rr >> 2) & 3) << 6);
    const int col = colb + (lc >> 2);
    const int row = rowbase + rr;
    const float4 sk = *(const float4*)(skip + (size_t)row * DIMM + col);
    const float4 bo = *(const float4*)(bout + col);
    float4 o4;
    o4.x = a4.x + sk.x + bo.x;
    o4.y = a4.y + sk.y + bo.y;
    o4.z = a4.z + sk.z + bo.z;
    o4.w = a4.w + sk.w + bo.w;
    *(float4*)(out + (size_t)row * DIMM + col) = o4;
  }
}

// ---- causal flash attention: 8-wave blocks (256 q-rows), ring-3 KV, exp2 softmax ----
__global__ __launch_bounds__(512) void attn_kernel(
    const __hip_bfloat16* __restrict__ qb, const __hip_bfloat16* __restrict__ kb,
    const __hip_bfloat16* __restrict__ vtb, __hip_bfloat16* __restrict__ ob) {
  __shared__ char sm[50176];  // K ring 3x8K | VT ring 3x8K | lred 1K
  float* lred = (float*)(sm + 49152);
  const int tid = threadIdx.x, lane = tid & 63, wid = tid >> 6;
  const int ln31 = lane & 31, hi = lane >> 5;
  const int head = blockIdx.x;
  const int qbi = (int)gridDim.y - 1 - (int)blockIdx.y;  // heavy blocks dispatch first
  const size_t hb = (size_t)head * (SEQ * HDIM);
  const int q0 = qbi * 256;
  const int qw = q0 + wid * 32;
  const int qg = qw + ln31;
  const int nt = qbi * 4 + 4;
  const char* Kg = (const char*)(kb + hb);
  const char* Vg = (const char*)(vtb + hb);

  bfv8 qf[4];
  {
    const char* Qp = (const char*)(qb + hb) + (size_t)(qw + ln31) * 128 + hi * 16;
#pragma unroll
    for (int j = 0; j < 4; ++j) qf[j] = *(const bfv8*)(Qp + j * 32);
  }

  f32x16 o0, o1;
#pragma unroll
  for (int i = 0; i < 16; ++i) { o0[i] = 0.f; o1[i] = 0.f; }
  float m_run = -1e30f, l_run = 0.f;
  const int swz = (ln31 & 7) << 4;

#define ATTN_STAGE(T, B)                                                            \
  {                                                                                 \
    const int kvs = (T)*64;                                                         \
    const int f = tid * 16;                                                         \
    const int row = f >> 7;                                                         \
    const int src = (f & 127) ^ ((row & 7) << 4);                                   \
    gload16(Kg + (size_t)(kvs + row) * 128 + src, sm + (B)*8192 + f);               \
    gload16(Vg + (size_t)row * 4096 + (size_t)kvs * 2 + src,                        \
            sm + 24576 + (B)*8192 + f);                                             \
  }

  ATTN_STAGE(0, 0);
  ATTN_STAGE(1, 1);
  asm volatile("s_waitcnt vmcnt(2)" ::: "memory");  // tile 0 landed; tile 1 in flight
  __builtin_amdgcn_s_barrier();

  for (int t = 0; t < nt; ++t) {
    const int kvb = t * 64;
    const bool st = (t + 2 < nt);
    if (st) ATTN_STAGE(t + 2, (t + 2) % 3);
    if (kvb <= qw + 31) {
      const char* ldsK = sm + (t % 3) * 8192;
      const char* ldsV = sm + 24576 + (t % 3) * 8192;
      f32x16 s0, s1;
#pragma unroll
      for (int i = 0; i < 16; ++i) { s0[i] = 0.f; s1[i] = 0.f; }
      __builtin_amdgcn_s_setprio(1);
#pragma unroll
      for (int j = 0; j < 4; ++j) {
        const int byt = j * 32 + hi * 16;
        const bfv8 k0 = *(const bfv8*)(ldsK + ln31 * 128 + (byt ^ swz));
        const bfv8 k1 = *(const bfv8*)(ldsK + (32 + ln31) * 128 + (byt ^ swz));
        s0 = mfma32(k0, qf[j], s0);
        s1 = mfma32(k1, qf[j], s1);
      }
      __builtin_amdgcn_s_setprio(0);
      float p[32];
#pragma unroll
      for (int r = 0; r < 16; ++r) { p[r] = s0[r]; p[16 + r] = s1[r]; }
      if (kvb + 63 > qw) {  // diagonal tile for this wave (compare vs MIN q-row)
#pragma unroll
        for (int r = 0; r < 16; ++r) {
          const int kvo = (r & 3) + 8 * (r >> 2) + 4 * hi;
          if (kvb + kvo > qg) p[r] = -1e30f;
          if (kvb + 32 + kvo > qg) p[16 + r] = -1e30f;
        }
      }
      float mx = p[0];
#pragma unroll
      for (int r = 1; r < 32; ++r) mx = fmaxf(mx, p[r]);
      mx = fmaxf(mx, __shfl_xor(mx, 32));
      if (!__all(mx <= m_run + 8.0f)) {  // defer-max: P bounded by 2^8
        const float mn = fmaxf(m_run, mx);
        const float al = __builtin_amdgcn_exp2f(m_run - mn);
        m_run = mn;
        l_run *= al;
        lred[wid * 32 + ln31] = al;
        asm volatile("s_waitcnt lgkmcnt(0)" ::: "memory");
        __builtin_amdgcn_sched_barrier(0);
#pragma unroll
        for (int r = 0; r < 16; ++r) {
          const float a = lred[wid * 32 + (r & 3) + 8 * (r >> 2) + 4 * hi];
          o0[r] *= a;
          o1[r] *= a;
        }
      }
      float ps = 0.f;
#pragma unroll
      for (int r = 0; r < 32; ++r) {
        p[r] = __builtin_amdgcn_exp2f(p[r] - m_run);
        ps += p[r];
      }
      ps += __shfl_xor(ps, 32);
      l_run += ps;
      unsigned c[16];
#pragma unroll
      for (int i = 0; i < 16; ++i) {
        unsigned rr;
        asm("v_cvt_pk_bf16_f32 %0, %1, %2" : "=v"(rr) : "v"(p[2 * i]), "v"(p[2 * i + 1]));
        c[i] = rr;
      }
      bfv8 paf[4];
#pragma unroll
      for (int fI = 0; fI < 4; ++fI) {
        unsigned a0 = c[fI * 4 + 0], b0 = c[fI * 4 + 2];
        unsigned a1 = c[fI * 4 + 1], b1 = c[fI * 4 + 3];
        swap32(a0, b0, hi);
        swap32(a1, b1, hi);
        union { unsigned u[4]; bfv8 v; } w;
        w.u[0] = a0; w.u[1] = a1; w.u[2] = b0; w.u[3] = b1;
        paf[fI] = w.v;
      }
      __builtin_amdgcn_s_setprio(1);
#pragma unroll
      for (int ss = 0; ss < 4; ++ss) {
        const int byt = ss * 32 + hi * 16;
        const bfv8 v0 = *(const bfv8*)(ldsV + ln31 * 128 + (byt ^ swz));
        const bfv8 v1 = *(const bfv8*)(ldsV + (32 + ln31) * 128 + (byt ^ swz));
        o0 = mfma32(paf[ss], v0, o0);
        o1 = mfma32(paf[ss], v1, o1);
      }
      __builtin_amdgcn_s_setprio(0);
    }
    if (st) {
      asm volatile("s_waitcnt vmcnt(2)" ::: "memory");  // t+1 landed; t+2 in flight
    } else if (t + 1 < nt) {
      asm volatile("s_waitcnt vmcnt(0)" ::: "memory");  // drain final tile
    }
    asm volatile("" ::: "memory");
    __builtin_amdgcn_s_barrier();
  }
#undef ATTN_STAGE

  lred[wid * 32 + ln31] = l_run;
  asm volatile("s_waitcnt lgkmcnt(0)" ::: "memory");
  __builtin_amdgcn_sched_barrier(0);
  const int nidx = head >> 5, hh = head & 31;
#pragma unroll
  for (int r = 0; r < 16; ++r) {
    const int qrow = qw + (r & 3) + 8 * (r >> 2) + 4 * hi;
    const float inv = 1.0f / lred[wid * 32 + (r & 3) + 8 * (r >> 2) + 4 * hi];
    __hip_bfloat16* dst = ob + ((size_t)nidx * SEQ + qrow) * DIMM + hh * 64;
    dst[ln31] = __float2bfloat16(o0[r] * inv);
    dst[32 + ln31] = __float2bfloat16(o1[r] * inv);
  }
}

extern "C" void kernel_launch(void* const* d_in, const int* in_sizes, int n_in,
                              void* d_out, int out_size, void* d_ws, size_t ws_size,
                              hipStream_t stream) {
  const float* x = (const float*)d_in[0];
  const float* ln_w = (const float*)d_in[1];
  const float* ln_b = (const float*)d_in[2];
  const float* w_qkv = (const float*)d_in[3];
  const float* b_qkv = (const float*)d_in[4];
  const float* w_out = (const float*)d_in[5];
  const float* b_out = (const float*)d_in[6];
  float* out = (float*)d_out;

  char* ws = (char*)d_ws;
  size_t off = 0;
  auto alloc = [&](size_t bytes) -> char* {
    char* p = ws + off;
    off += (bytes + 255) & ~(size_t)255;
    return p;
  };
  __hip_bfloat16* h = (__hip_bfloat16*)alloc((size_t)ROWS * DIMM * 2);
  __hip_bfloat16* wqkvT = (__hip_bfloat16*)alloc((size_t)3 * DIMM * DIMM * 2);
  __hip_bfloat16* woutT = (__hip_bfloat16*)alloc((size_t)DIMM * DIMM * 2);
  __hip_bfloat16* qbuf = (__hip_bfloat16*)alloc((size_t)ROWS * DIMM * 2);
  __hip_bfloat16* kbuf = (__hip_bfloat16*)alloc((size_t)ROWS * DIMM * 2);
  __hip_bfloat16* vtbuf = (__hip_bfloat16*)alloc((size_t)ROWS * DIMM * 2);
  __hip_bfloat16* obuf = (__hip_bfloat16*)alloc((size_t)ROWS * DIMM * 2);
  float* ct = (float*)alloc((size_t)SEQ * NFREQ * 4);
  float* st = (float*)alloc((size_t)SEQ * NFREQ * 4);

  prep_kernel<<<dim3(PB_TOTAL), dim3(256), 0, stream>>>(
      x, ln_w, ln_b, h, w_qkv, wqkvT, w_out, woutT, ct, st);
  gemm_qkv_kernel<<<dim3(3 * DIMM / 128, ROWS / 256), dim3(512), 0, stream>>>(
      h, wqkvT, b_qkv, ct, st, qbuf, kbuf, vtbuf);
  attn_kernel<<<dim3(NBATCH * NHEADS, SEQ / 256), dim3(512), 0, stream>>>(
      qbuf, kbuf, vtbuf, obuf);
  gemm_out_kernel<<<dim3(DIMM / 128, ROWS / 256), dim3(512), 0, stream>>>(
      obuf, woutT, b_out, x, out);
}